// Round 1
// baseline (4975.693 us; speedup 1.0000x reference)
//
#include <hip/hip_runtime.h>
#include <math.h>

#define NCH 128
#define TE 64

__device__ __forceinline__ float gelu_exact(float v) {
    return 0.5f * v * (1.0f + erff(v * 0.70710678118654752f));
}

// ---------------- Kernel 1: h = x @ w1 + b1 -> h (stored in d_out) ----------
__global__ __launch_bounds__(256) void k_atomwise1(
    const float* __restrict__ x, const float* __restrict__ w1,
    const float* __restrict__ b1, float* __restrict__ h, int N)
{
    __shared__ float xs[16][NCH];
    const int row0 = blockIdx.x * 16;
    const int tid = threadIdx.x;

    #pragma unroll
    for (int t = 0; t < 8; ++t) {
        int idx = tid + t * 256;
        int r = idx >> 7, c = idx & 127;
        int gr = row0 + r;
        xs[r][c] = (gr < N) ? x[(size_t)gr * NCH + c] : 0.f;
    }
    __syncthreads();

    const int j = tid & 127;
    const int rg = tid >> 7;          // 0..1, 8 rows each
    float acc[8];
    #pragma unroll
    for (int i = 0; i < 8; ++i) acc[i] = 0.f;

    for (int k = 0; k < NCH; ++k) {
        float wv = w1[(size_t)k * NCH + j];
        #pragma unroll
        for (int i = 0; i < 8; ++i)
            acc[i] = fmaf(xs[rg * 8 + i][k], wv, acc[i]);
    }
    float bv = b1[j];
    #pragma unroll
    for (int i = 0; i < 8; ++i) {
        int gr = row0 + rg * 8 + i;
        if (gr < N) h[(size_t)gr * NCH + j] = acc[i] + bv;
    }
}

// ---------------- Kernel 2: edge message MLP + scatter-add ------------------
// msg_in = [sin(16) | cos(16) | edge_attr(128) | h[src](128)]  (288)
// m = gelu(msg_in@mw1+mb1); m = gelu(m@mw2+mb2); m = m@mw3+mb3
// agg[dst] += m
__global__ __launch_bounds__(256) void k_edges(
    const int* __restrict__ ei, const float* __restrict__ eattr,
    const float* __restrict__ xpos, const float* __restrict__ h,
    const float* __restrict__ mw1, const float* __restrict__ mb1,
    const float* __restrict__ mw2, const float* __restrict__ mb2,
    const float* __restrict__ mw3, const float* __restrict__ mb3,
    float* __restrict__ agg, int E)
{
    __shared__ __align__(16) float As[TE][292];   // 288 + pad
    __shared__ float Ws[32][NCH];
    __shared__ int srcS[TE];
    __shared__ int dstS[TE];

    const int tid = threadIdx.x;
    const int e0 = blockIdx.x * TE;

    // phase 1: metadata + RBF sin/cos (one thread per edge)
    if (tid < TE) {
        int e = e0 + tid;
        int s = 0, d = -1;
        float r = 0.f;
        if (e < E) {
            s = ei[e];
            d = ei[E + e];
            float dx = xpos[d * 3 + 0] - xpos[s * 3 + 0];
            float dy = xpos[d * 3 + 1] - xpos[s * 3 + 1];
            float dz = xpos[d * 3 + 2] - xpos[s * 3 + 2];
            r = sqrtf(dx * dx + dy * dy + dz * dz);
        }
        srcS[tid] = s;
        dstS[tid] = d;
        #pragma unroll
        for (int i = 0; i < 16; ++i) {
            // omega_i = 10 * 128^(1 - i/8) = 10 * 2^(7 - 0.875 i)
            float om = 10.f * exp2f(7.0f - 0.875f * (float)i);
            float f = r * om;
            As[tid][i]      = sinf(f);
            As[tid][16 + i] = cosf(f);
        }
    }
    __syncthreads();

    // phase 2: stage edge_attr and h[src] (coalesced, 2 edges x 128 cols)
    {
        const int half = tid >> 7;     // 0..1
        const int c = tid & 127;
        for (int ee = 0; ee < TE; ee += 2) {
            int le = ee + half;
            int e = e0 + le;
            if (e < E) {
                As[le][32 + c]  = eattr[(size_t)e * NCH + c];
                As[le][160 + c] = h[(size_t)srcS[le] * NCH + c];
            } else {
                As[le][32 + c]  = 0.f;
                As[le][160 + c] = 0.f;
            }
        }
    }

    const int jl = tid & 31;     // col lane
    const int g  = tid >> 5;     // edge group 0..7, 8 edges each
    float acc[8][4];

    auto run_layer = [&](const float* __restrict__ Wg, int K) {
        #pragma unroll
        for (int i = 0; i < 8; ++i)
            #pragma unroll
            for (int c = 0; c < 4; ++c) acc[i][c] = 0.f;
        for (int k0 = 0; k0 < K; k0 += 32) {
            __syncthreads();   // previous consumers of Ws / producers of As done
            #pragma unroll
            for (int t = 0; t < 16; ++t) {
                int idx = tid + t * 256;
                Ws[idx >> 7][idx & 127] =
                    Wg[(size_t)(k0 + (idx >> 7)) * NCH + (idx & 127)];
            }
            __syncthreads();
            #pragma unroll
            for (int kk = 0; kk < 32; kk += 4) {
                float4 a[8];
                #pragma unroll
                for (int i = 0; i < 8; ++i)
                    a[i] = *reinterpret_cast<const float4*>(&As[g * 8 + i][k0 + kk]);
                #pragma unroll
                for (int u = 0; u < 4; ++u) {
                    float w0 = Ws[kk + u][jl];
                    float w1v = Ws[kk + u][jl + 32];
                    float w2v = Ws[kk + u][jl + 64];
                    float w3v = Ws[kk + u][jl + 96];
                    #pragma unroll
                    for (int i = 0; i < 8; ++i) {
                        float av = (&a[i].x)[u];
                        acc[i][0] = fmaf(av, w0, acc[i][0]);
                        acc[i][1] = fmaf(av, w1v, acc[i][1]);
                        acc[i][2] = fmaf(av, w2v, acc[i][2]);
                        acc[i][3] = fmaf(av, w3v, acc[i][3]);
                    }
                }
            }
        }
    };

    // layer 1 (K=288), gelu, write back into As[:, 0:128]
    run_layer(mw1, 288);
    #pragma unroll
    for (int i = 0; i < 8; ++i)
        #pragma unroll
        for (int c = 0; c < 4; ++c) {
            int j = jl + 32 * c;
            As[g * 8 + i][j] = gelu_exact(acc[i][c] + mb1[j]);
        }

    // layer 2 (K=128), gelu, write back
    run_layer(mw2, 128);
    #pragma unroll
    for (int i = 0; i < 8; ++i)
        #pragma unroll
        for (int c = 0; c < 4; ++c) {
            int j = jl + 32 * c;
            As[g * 8 + i][j] = gelu_exact(acc[i][c] + mb2[j]);
        }

    // layer 3 (K=128) + bias + scatter-add
    run_layer(mw3, 128);
    #pragma unroll
    for (int i = 0; i < 8; ++i) {
        int d = dstS[g * 8 + i];
        if (d >= 0) {
            #pragma unroll
            for (int c = 0; c < 4; ++c) {
                int j = jl + 32 * c;
                atomicAdd(&agg[(size_t)d * NCH + j], acc[i][c] + mb3[j]);
            }
        }
    }
}

// ---------------- Kernel 3: out = relu((h+agg)@w2+b2)@w3+b3 ------------------
// NOTE: h and out alias (both d_out). Each block only reads rows it writes,
// with a barrier between all reads and all writes -> safe. No __restrict__
// on h/out.
__global__ __launch_bounds__(256) void k_out(
    const float* h, const float* __restrict__ agg,
    const float* __restrict__ w2, const float* __restrict__ b2,
    const float* __restrict__ w3, const float* __restrict__ b3,
    float* out, int N)
{
    __shared__ float hs[16][NCH];
    __shared__ float ts[16][NCH];
    const int row0 = blockIdx.x * 16;
    const int tid = threadIdx.x;

    #pragma unroll
    for (int t = 0; t < 8; ++t) {
        int idx = tid + t * 256;
        int r = idx >> 7, c = idx & 127;
        int gr = row0 + r;
        hs[r][c] = (gr < N)
            ? h[(size_t)gr * NCH + c] + agg[(size_t)gr * NCH + c] : 0.f;
    }
    __syncthreads();

    const int j = tid & 127;
    const int rg = tid >> 7;
    float acc[8];
    #pragma unroll
    for (int i = 0; i < 8; ++i) acc[i] = 0.f;
    for (int k = 0; k < NCH; ++k) {
        float wv = w2[(size_t)k * NCH + j];
        #pragma unroll
        for (int i = 0; i < 8; ++i)
            acc[i] = fmaf(hs[rg * 8 + i][k], wv, acc[i]);
    }
    float bv = b2[j];
    #pragma unroll
    for (int i = 0; i < 8; ++i)
        ts[rg * 8 + i][j] = fmaxf(acc[i] + bv, 0.f);
    __syncthreads();

    float acc2[8];
    #pragma unroll
    for (int i = 0; i < 8; ++i) acc2[i] = 0.f;
    for (int k = 0; k < NCH; ++k) {
        float wv = w3[(size_t)k * NCH + j];
        #pragma unroll
        for (int i = 0; i < 8; ++i)
            acc2[i] = fmaf(ts[rg * 8 + i][k], wv, acc2[i]);
    }
    float b3v = b3[j];
    #pragma unroll
    for (int i = 0; i < 8; ++i) {
        int gr = row0 + rg * 8 + i;
        if (gr < N) out[(size_t)gr * NCH + j] = acc2[i] + b3v;
    }
}

extern "C" void kernel_launch(void* const* d_in, const int* in_sizes, int n_in,
                              void* d_out, int out_size, void* d_ws, size_t ws_size,
                              hipStream_t stream)
{
    const float* x     = (const float*)d_in[0];
    const int*   ei    = (const int*)d_in[1];
    const float* eattr = (const float*)d_in[2];
    const float* xpos  = (const float*)d_in[3];
    const float* w1    = (const float*)d_in[4];
    const float* b1    = (const float*)d_in[5];
    const float* mw1   = (const float*)d_in[6];
    const float* mb1   = (const float*)d_in[7];
    const float* mw2   = (const float*)d_in[8];
    const float* mb2   = (const float*)d_in[9];
    const float* mw3   = (const float*)d_in[10];
    const float* mb3   = (const float*)d_in[11];
    const float* w2    = (const float*)d_in[12];
    const float* b2    = (const float*)d_in[13];
    const float* w3    = (const float*)d_in[14];
    const float* b3    = (const float*)d_in[15];

    const int N = in_sizes[0] / NCH;
    const int E = in_sizes[1] / 2;

    float* h   = (float*)d_out;   // scratch: atomwise1 output lives in d_out
    float* agg = (float*)d_ws;    // segment-sum accumulator

    hipMemsetAsync(agg, 0, (size_t)N * NCH * sizeof(float), stream);

    k_atomwise1<<<(N + 15) / 16, 256, 0, stream>>>(x, w1, b1, h, N);
    k_edges<<<(E + TE - 1) / TE, 256, 0, stream>>>(
        ei, eattr, xpos, h, mw1, mb1, mw2, mb2, mw3, mb3, agg, E);
    k_out<<<(N + 15) / 16, 256, 0, stream>>>(h, agg, w2, b2, w3, b3,
                                             (float*)d_out, N);
}

// Round 2
// 864.805 us; speedup vs baseline: 5.7535x; 5.7535x over previous
//
#include <hip/hip_runtime.h>
#include <math.h>

#define NCH 128
#define TE 64
#define AP 296   // padded msg_in row (f16 elems): 592B row, 16B aligned, 2-way banks max
#define WP 40    // padded W^T row (f16 elems): 80B row, 16B aligned, 2-way banks max

typedef __attribute__((ext_vector_type(8))) _Float16 half8;
typedef __attribute__((ext_vector_type(4))) _Float16 half4;
typedef __attribute__((ext_vector_type(4))) float f32x4;

__device__ __forceinline__ float gelu_exact(float v) {
    return 0.5f * v * (1.0f + erff(v * 0.70710678118654752f));
}

// ============ prep: W[K][128] fp32 -> k-chunked transposed f16 [K/32][128][32]
__global__ __launch_bounds__(256) void k_prep(const float* __restrict__ W,
                                              _Float16* __restrict__ out, int total) {
    int idx = blockIdx.x * 256 + threadIdx.x;
    if (idx >= total) return;
    int k = idx >> 7, n = idx & 127;
    out[(size_t)(k >> 5) * 4096 + n * 32 + (k & 31)] = (_Float16)W[idx];
}

// ============ Kernel 1: h = x @ w1 + b1 -> h (d_out) and h2 (gather copy, ws)
__global__ __launch_bounds__(256) void k_atomwise1(
    const float* __restrict__ x, const float* __restrict__ w1,
    const float* __restrict__ b1, float* __restrict__ h,
    float* __restrict__ h2, int N)
{
    __shared__ float xs[16][NCH];
    const int row0 = blockIdx.x * 16;
    const int tid = threadIdx.x;

    #pragma unroll
    for (int t = 0; t < 8; ++t) {
        int idx = tid + t * 256;
        int r = idx >> 7, c = idx & 127;
        int gr = row0 + r;
        xs[r][c] = (gr < N) ? x[(size_t)gr * NCH + c] : 0.f;
    }
    __syncthreads();

    const int j = tid & 127;
    const int rg = tid >> 7;
    float acc[8];
    #pragma unroll
    for (int i = 0; i < 8; ++i) acc[i] = 0.f;

    for (int k = 0; k < NCH; ++k) {
        float wv = w1[(size_t)k * NCH + j];
        #pragma unroll
        for (int i = 0; i < 8; ++i)
            acc[i] = fmaf(xs[rg * 8 + i][k], wv, acc[i]);
    }
    float bv = b1[j];
    #pragma unroll
    for (int i = 0; i < 8; ++i) {
        int gr = row0 + rg * 8 + i;
        if (gr < N) {
            float v = acc[i] + bv;
            h[(size_t)gr * NCH + j]  = v;
            h2[(size_t)gr * NCH + j] = v;
        }
    }
}

// ============ Kernel 2 (fast): MFMA edge MLP, atomics straight into h (d_out)
__global__ __launch_bounds__(256, 2) void k_edges_mfma(
    const int* __restrict__ ei, const float* __restrict__ eattr,
    const float* __restrict__ xpos, const float* __restrict__ h2,
    float* h,   // accumulate target (aliases d_out; atomics only)
    const _Float16* __restrict__ w1c, const _Float16* __restrict__ w2c,
    const _Float16* __restrict__ w3c,
    const float* __restrict__ mb1, const float* __restrict__ mb2,
    const float* __restrict__ mb3, int E)
{
    __shared__ __align__(16) _Float16 As[TE][AP];        // 37888 B
    __shared__ __align__(16) _Float16 Ws[2][128][WP];    // 20480 B
    __shared__ int srcS[TE], dstS[TE];

    const int tid  = threadIdx.x;
    const int e0   = blockIdx.x * TE;
    const int lane = tid & 63;
    const int w    = tid >> 6;       // wave 0..3
    const int lrow = lane & 15;
    const int lk8  = lane >> 4;      // 0..3
    const int n0   = w * 32;         // wave's output-col base

    // ---- phase 1: per-edge metadata + RBF sin/cos
    if (tid < TE) {
        int e = e0 + tid;
        int s = 0, d = -1;
        float r = 0.f;
        if (e < E) {
            s = ei[e];
            d = ei[E + e];
            float dx = xpos[d * 3 + 0] - xpos[s * 3 + 0];
            float dy = xpos[d * 3 + 1] - xpos[s * 3 + 1];
            float dz = xpos[d * 3 + 2] - xpos[s * 3 + 2];
            r = sqrtf(dx * dx + dy * dy + dz * dz);
        }
        srcS[tid] = s;
        dstS[tid] = d;
        #pragma unroll
        for (int i = 0; i < 16; ++i) {
            float om = 10.f * exp2f(7.0f - 0.875f * (float)i);  // 10*128^(1-i/8)
            float f = r * om;
            As[tid][i]      = (_Float16)sinf(f);
            As[tid][16 + i] = (_Float16)cosf(f);
        }
    }
    __syncthreads();

    // ---- phase 2: stage edge_attr + h2[src] (f32 -> f16), and W chunk 0
    #pragma unroll
    for (int t = 0; t < 8; ++t) {
        int idx = tid + t * 256;
        int row = idx >> 5, f4 = idx & 31;
        int e = e0 + row;
        float4 va = {0.f, 0.f, 0.f, 0.f}, vh = {0.f, 0.f, 0.f, 0.f};
        if (e < E) {
            va = *(const float4*)(eattr + (size_t)e * NCH + f4 * 4);
            vh = *(const float4*)(h2 + (size_t)srcS[row] * NCH + f4 * 4);
        }
        half4 pa = {(_Float16)va.x, (_Float16)va.y, (_Float16)va.z, (_Float16)va.w};
        half4 ph = {(_Float16)vh.x, (_Float16)vh.y, (_Float16)vh.z, (_Float16)vh.w};
        *(half4*)&As[row][32 + f4 * 4]  = pa;
        *(half4*)&As[row][160 + f4 * 4] = ph;
    }
    {
        const uint4* s = (const uint4*)w1c;
        uint4 v0 = s[tid], v1 = s[tid + 256];
        *(uint4*)&Ws[0][tid >> 2][(tid & 3) * 8]        = v0;
        *(uint4*)&Ws[0][64 + (tid >> 2)][(tid & 3) * 8] = v1;
    }
    __syncthreads();

    f32x4 acc[4][2];
    #pragma unroll
    for (int mb = 0; mb < 4; ++mb)
        #pragma unroll
        for (int nf = 0; nf < 2; ++nf)
            acc[mb][nf] = (f32x4){0.f, 0.f, 0.f, 0.f};

    auto midEpilogue = [&](const float* __restrict__ mbv) {
        float bi0 = mbv[n0 + lrow], bi1 = mbv[n0 + 16 + lrow];
        __syncthreads();   // everyone done reading As for this layer
        #pragma unroll
        for (int mb = 0; mb < 4; ++mb)
            #pragma unroll
            for (int nf = 0; nf < 2; ++nf) {
                float bb = nf ? bi1 : bi0;
                #pragma unroll
                for (int q = 0; q < 4; ++q) {
                    float g = gelu_exact(acc[mb][nf][q] + bb);
                    As[mb * 16 + lk8 * 4 + q][n0 + nf * 16 + lrow] = (_Float16)g;
                }
                acc[mb][nf] = (f32x4){0.f, 0.f, 0.f, 0.f};
            }
    };

    // ---- main loop: 17 K-chunks (9 for layer1, 4+4 for layers 2,3)
    for (int i = 0; i < 17; ++i) {
        const int b = i & 1;
        uint4 pv0, pv1;
        if (i < 16) {
            int j = i + 1;
            const _Float16* nw = (j < 9)  ? (w1c + j * 4096)
                               : (j < 13) ? (w2c + (j - 9) * 4096)
                                          : (w3c + (j - 13) * 4096);
            const uint4* s = (const uint4*)nw;
            pv0 = s[tid]; pv1 = s[tid + 256];
        }
        const int lc = (i < 9) ? i : (i < 13) ? (i - 9) : (i - 13);

        half8 av[4], bv[2];
        #pragma unroll
        for (int mb = 0; mb < 4; ++mb)
            av[mb] = *(const half8*)&As[mb * 16 + lrow][lc * 32 + lk8 * 8];
        #pragma unroll
        for (int nf = 0; nf < 2; ++nf)
            bv[nf] = *(const half8*)&Ws[b][n0 + nf * 16 + lrow][lk8 * 8];
        #pragma unroll
        for (int mb = 0; mb < 4; ++mb)
            #pragma unroll
            for (int nf = 0; nf < 2; ++nf)
                acc[mb][nf] = __builtin_amdgcn_mfma_f32_16x16x32_f16(
                    av[mb], bv[nf], acc[mb][nf], 0, 0, 0);

        if (i < 16) {   // safe: last reads of buf b^1 were iter i-1, barrier since
            *(uint4*)&Ws[b ^ 1][tid >> 2][(tid & 3) * 8]        = pv0;
            *(uint4*)&Ws[b ^ 1][64 + (tid >> 2)][(tid & 3) * 8] = pv1;
        }
        if (i == 8)       midEpilogue(mb1);
        else if (i == 12) midEpilogue(mb2);
        __syncthreads();
    }

    // ---- final epilogue: bias + scatter-add into h
    {
        float bi0 = mb3[n0 + lrow], bi1 = mb3[n0 + 16 + lrow];
        #pragma unroll
        for (int mb = 0; mb < 4; ++mb)
            #pragma unroll
            for (int q = 0; q < 4; ++q) {
                int el = mb * 16 + lk8 * 4 + q;
                int d = dstS[el];
                if (d >= 0) {
                    atomicAdd(h + (size_t)d * NCH + n0 + lrow,      acc[mb][0][q] + bi0);
                    atomicAdd(h + (size_t)d * NCH + n0 + 16 + lrow, acc[mb][1][q] + bi1);
                }
            }
    }
}

// ============ Kernel 2 (slow fallback, round-1 fp32 with separate agg) =======
__global__ __launch_bounds__(256) void k_edges_f32(
    const int* __restrict__ ei, const float* __restrict__ eattr,
    const float* __restrict__ xpos, const float* __restrict__ h,
    const float* __restrict__ mw1, const float* __restrict__ mb1,
    const float* __restrict__ mw2, const float* __restrict__ mb2,
    const float* __restrict__ mw3, const float* __restrict__ mb3,
    float* __restrict__ agg, int E)
{
    __shared__ __align__(16) float Asf[TE][292];
    __shared__ float Wsf[32][NCH];
    __shared__ int srcS[TE];
    __shared__ int dstS[TE];

    const int tid = threadIdx.x;
    const int e0 = blockIdx.x * TE;

    if (tid < TE) {
        int e = e0 + tid;
        int s = 0, d = -1;
        float r = 0.f;
        if (e < E) {
            s = ei[e]; d = ei[E + e];
            float dx = xpos[d * 3 + 0] - xpos[s * 3 + 0];
            float dy = xpos[d * 3 + 1] - xpos[s * 3 + 1];
            float dz = xpos[d * 3 + 2] - xpos[s * 3 + 2];
            r = sqrtf(dx * dx + dy * dy + dz * dz);
        }
        srcS[tid] = s; dstS[tid] = d;
        #pragma unroll
        for (int i = 0; i < 16; ++i) {
            float om = 10.f * exp2f(7.0f - 0.875f * (float)i);
            float f = r * om;
            Asf[tid][i] = sinf(f); Asf[tid][16 + i] = cosf(f);
        }
    }
    __syncthreads();
    {
        const int half = tid >> 7;
        const int c = tid & 127;
        for (int ee = 0; ee < TE; ee += 2) {
            int le = ee + half;
            int e = e0 + le;
            if (e < E) {
                Asf[le][32 + c]  = eattr[(size_t)e * NCH + c];
                Asf[le][160 + c] = h[(size_t)srcS[le] * NCH + c];
            } else { Asf[le][32 + c] = 0.f; Asf[le][160 + c] = 0.f; }
        }
    }
    const int jl = tid & 31;
    const int g  = tid >> 5;
    float acc[8][4];
    auto run_layer = [&](const float* __restrict__ Wg, int K) {
        #pragma unroll
        for (int i = 0; i < 8; ++i)
            #pragma unroll
            for (int c = 0; c < 4; ++c) acc[i][c] = 0.f;
        for (int k0 = 0; k0 < K; k0 += 32) {
            __syncthreads();
            #pragma unroll
            for (int t = 0; t < 16; ++t) {
                int idx = tid + t * 256;
                Wsf[idx >> 7][idx & 127] =
                    Wg[(size_t)(k0 + (idx >> 7)) * NCH + (idx & 127)];
            }
            __syncthreads();
            #pragma unroll
            for (int kk = 0; kk < 32; kk += 4) {
                float4 a[8];
                #pragma unroll
                for (int i = 0; i < 8; ++i)
                    a[i] = *reinterpret_cast<const float4*>(&Asf[g * 8 + i][k0 + kk]);
                #pragma unroll
                for (int u = 0; u < 4; ++u) {
                    float w0 = Wsf[kk + u][jl];
                    float w1v = Wsf[kk + u][jl + 32];
                    float w2v = Wsf[kk + u][jl + 64];
                    float w3v = Wsf[kk + u][jl + 96];
                    #pragma unroll
                    for (int i = 0; i < 8; ++i) {
                        float avv = (&a[i].x)[u];
                        acc[i][0] = fmaf(avv, w0, acc[i][0]);
                        acc[i][1] = fmaf(avv, w1v, acc[i][1]);
                        acc[i][2] = fmaf(avv, w2v, acc[i][2]);
                        acc[i][3] = fmaf(avv, w3v, acc[i][3]);
                    }
                }
            }
        }
    };
    run_layer(mw1, 288);
    #pragma unroll
    for (int i = 0; i < 8; ++i)
        #pragma unroll
        for (int c = 0; c < 4; ++c) {
            int j = jl + 32 * c;
            Asf[g * 8 + i][j] = gelu_exact(acc[i][c] + mb1[j]);
        }
    run_layer(mw2, 128);
    #pragma unroll
    for (int i = 0; i < 8; ++i)
        #pragma unroll
        for (int c = 0; c < 4; ++c) {
            int j = jl + 32 * c;
            Asf[g * 8 + i][j] = gelu_exact(acc[i][c] + mb2[j]);
        }
    run_layer(mw3, 128);
    #pragma unroll
    for (int i = 0; i < 8; ++i) {
        int d = dstS[g * 8 + i];
        if (d >= 0) {
            #pragma unroll
            for (int c = 0; c < 4; ++c) {
                int j = jl + 32 * c;
                atomicAdd(&agg[(size_t)d * NCH + j], acc[i][c] + mb3[j]);
            }
        }
    }
}

// ============ Kernel 3: out = relu(h@w2+b2)@w3+b3 (in place on d_out) ========
// aggOpt: nullptr in fast path (h already contains h+agg)
__global__ __launch_bounds__(256) void k_out(
    const float* h, const float* aggOpt,
    const float* __restrict__ w2, const float* __restrict__ b2,
    const float* __restrict__ w3, const float* __restrict__ b3,
    float* out, int N)
{
    __shared__ float hs[16][NCH];
    __shared__ float ts[16][NCH];
    const int row0 = blockIdx.x * 16;
    const int tid = threadIdx.x;

    #pragma unroll
    for (int t = 0; t < 8; ++t) {
        int idx = tid + t * 256;
        int r = idx >> 7, c = idx & 127;
        int gr = row0 + r;
        float v = 0.f;
        if (gr < N) {
            v = h[(size_t)gr * NCH + c];
            if (aggOpt) v += aggOpt[(size_t)gr * NCH + c];
        }
        hs[r][c] = v;
    }
    __syncthreads();

    const int j = tid & 127;
    const int rg = tid >> 7;
    float acc[8];
    #pragma unroll
    for (int i = 0; i < 8; ++i) acc[i] = 0.f;
    for (int k = 0; k < NCH; ++k) {
        float wv = w2[(size_t)k * NCH + j];
        #pragma unroll
        for (int i = 0; i < 8; ++i)
            acc[i] = fmaf(hs[rg * 8 + i][k], wv, acc[i]);
    }
    float bv = b2[j];
    #pragma unroll
    for (int i = 0; i < 8; ++i)
        ts[rg * 8 + i][j] = fmaxf(acc[i] + bv, 0.f);
    __syncthreads();

    float acc2[8];
    #pragma unroll
    for (int i = 0; i < 8; ++i) acc2[i] = 0.f;
    for (int k = 0; k < NCH; ++k) {
        float wv = w3[(size_t)k * NCH + j];
        #pragma unroll
        for (int i = 0; i < 8; ++i)
            acc2[i] = fmaf(ts[rg * 8 + i][k], wv, acc2[i]);
    }
    float b3v = b3[j];
    #pragma unroll
    for (int i = 0; i < 8; ++i) {
        int gr = row0 + rg * 8 + i;
        if (gr < N) out[(size_t)gr * NCH + j] = acc2[i] + b3v;
    }
}

extern "C" void kernel_launch(void* const* d_in, const int* in_sizes, int n_in,
                              void* d_out, int out_size, void* d_ws, size_t ws_size,
                              hipStream_t stream)
{
    const float* x     = (const float*)d_in[0];
    const int*   ei    = (const int*)d_in[1];
    const float* eattr = (const float*)d_in[2];
    const float* xpos  = (const float*)d_in[3];
    const float* w1    = (const float*)d_in[4];
    const float* b1    = (const float*)d_in[5];
    const float* mw1   = (const float*)d_in[6];
    const float* mb1   = (const float*)d_in[7];
    const float* mw2   = (const float*)d_in[8];
    const float* mb2   = (const float*)d_in[9];
    const float* mw3   = (const float*)d_in[10];
    const float* mb3   = (const float*)d_in[11];
    const float* w2    = (const float*)d_in[12];
    const float* b2    = (const float*)d_in[13];
    const float* w3    = (const float*)d_in[14];
    const float* b3    = (const float*)d_in[15];

    const int N = in_sizes[0] / NCH;
    const int E = in_sizes[1] / 2;

    float* h  = (float*)d_out;
    float* h2 = (float*)d_ws;
    const size_t h2_bytes = (size_t)N * NCH * sizeof(float);
    const size_t wbytes = (size_t)(288 + 128 + 128) * 128 * sizeof(_Float16);
    const bool fast = ws_size >= h2_bytes + wbytes;

    if (fast) {
        _Float16* w1c = (_Float16*)((char*)d_ws + h2_bytes);
        _Float16* w2c = w1c + 288 * 128;
        _Float16* w3c = w2c + 128 * 128;
        k_prep<<<144, 256, 0, stream>>>(mw1, w1c, 288 * 128);
        k_prep<<<64, 256, 0, stream>>>(mw2, w2c, 128 * 128);
        k_prep<<<64, 256, 0, stream>>>(mw3, w3c, 128 * 128);
        k_atomwise1<<<(N + 15) / 16, 256, 0, stream>>>(x, w1, b1, h, h2, N);
        k_edges_mfma<<<(E + TE - 1) / TE, 256, 0, stream>>>(
            ei, eattr, xpos, h2, h, w1c, w2c, w3c, mb1, mb2, mb3, E);
        k_out<<<(N + 15) / 16, 256, 0, stream>>>(h, nullptr, w2, b2, w3, b3,
                                                 (float*)d_out, N);
    } else {
        // round-1 fp32 fallback: agg in ws
        float* agg = (float*)d_ws;
        k_atomwise1<<<(N + 15) / 16, 256, 0, stream>>>(x, w1, b1, h, agg, N); // agg gets overwritten next
        hipMemsetAsync(agg, 0, (size_t)N * NCH * sizeof(float), stream);
        k_edges_f32<<<(E + TE - 1) / TE, 256, 0, stream>>>(
            ei, eattr, xpos, h, mw1, mb1, mw2, mb2, mw3, mb3, agg, E);
        k_out<<<(N + 15) / 16, 256, 0, stream>>>(h, agg, w2, b2, w3, b3,
                                                 (float*)d_out, N);
    }
}

// Round 3
// 638.354 us; speedup vs baseline: 7.7946x; 1.3547x over previous
//
#include <hip/hip_runtime.h>
#include <math.h>

#define NCH 128
#define TE 64
#define AP 296   // msg_in row pad (f16): 592B row = 148 words, %32=20 -> 2-way banks
#define WP 40    // W^T row pad (f16): 80B row, 16B aligned, 2-way banks
#define XP 136   // node-tile row pad (f16): 272B row = 68 words, %32=4 -> 2-way banks

typedef __attribute__((ext_vector_type(8))) _Float16 half8;
typedef __attribute__((ext_vector_type(4))) _Float16 half4;
typedef __attribute__((ext_vector_type(4))) float f32x4;

__device__ __forceinline__ float gelu_exact(float v) {
    return 0.5f * v * (1.0f + erff(v * 0.70710678118654752f));
}

// ============ prep: W[K][128] fp32 -> k-chunked transposed f16 [K/32][128][32]
__global__ __launch_bounds__(256) void k_prep(const float* __restrict__ W,
                                              _Float16* __restrict__ out, int total) {
    int idx = blockIdx.x * 256 + threadIdx.x;
    if (idx >= total) return;
    int k = idx >> 7, n = idx & 127;
    out[(size_t)(k >> 5) * 4096 + n * 32 + (k & 31)] = (_Float16)W[idx];
}

// ============ Kernel 1 (fast): h = x@w1+b1 via MFMA -> h fp32 (d_out) + h2 f16
__global__ __launch_bounds__(256, 4) void k_aw1_mfma(
    const float* __restrict__ x, const _Float16* __restrict__ wc,
    const float* __restrict__ b1, float* __restrict__ h,
    _Float16* __restrict__ h2, int N)
{
    __shared__ __align__(16) _Float16 Xs[64][XP];   // 17408 B
    __shared__ __align__(16) _Float16 Ws[128][WP];  // 10240 B

    const int tid  = threadIdx.x;
    const int row0 = blockIdx.x * 64;
    const int lane = tid & 63;
    const int w    = tid >> 6;
    const int lrow = lane & 15;
    const int lk8  = lane >> 4;
    const int n0   = w * 32;

    const uint4* wsrc = (const uint4*)wc;
    uint4 pv0 = wsrc[tid], pv1 = wsrc[tid + 256];

    #pragma unroll
    for (int t = 0; t < 8; ++t) {
        int idx = tid + t * 256;
        int r = idx >> 5, f4 = idx & 31;
        int gr = row0 + r;
        float4 v = {0.f, 0.f, 0.f, 0.f};
        if (gr < N) v = *(const float4*)(x + (size_t)gr * NCH + f4 * 4);
        half4 p = {(_Float16)v.x, (_Float16)v.y, (_Float16)v.z, (_Float16)v.w};
        *(half4*)&Xs[r][f4 * 4] = p;
    }
    *(uint4*)&Ws[tid >> 2][(tid & 3) * 8]        = pv0;
    *(uint4*)&Ws[64 + (tid >> 2)][(tid & 3) * 8] = pv1;
    __syncthreads();

    f32x4 acc[4][2];
    #pragma unroll
    for (int mb = 0; mb < 4; ++mb)
        #pragma unroll
        for (int nf = 0; nf < 2; ++nf) acc[mb][nf] = (f32x4){0.f, 0.f, 0.f, 0.f};

    for (int i = 0; i < 4; ++i) {
        if (i < 3) {
            const uint4* s = (const uint4*)(wc + (i + 1) * 4096);
            pv0 = s[tid]; pv1 = s[tid + 256];
        }
        half8 av[4], bv[2];
        #pragma unroll
        for (int mb = 0; mb < 4; ++mb)
            av[mb] = *(const half8*)&Xs[mb * 16 + lrow][i * 32 + lk8 * 8];
        #pragma unroll
        for (int nf = 0; nf < 2; ++nf)
            bv[nf] = *(const half8*)&Ws[n0 + nf * 16 + lrow][lk8 * 8];
        #pragma unroll
        for (int mb = 0; mb < 4; ++mb)
            #pragma unroll
            for (int nf = 0; nf < 2; ++nf)
                acc[mb][nf] = __builtin_amdgcn_mfma_f32_16x16x32_f16(
                    av[mb], bv[nf], acc[mb][nf], 0, 0, 0);
        __syncthreads();
        if (i < 3) {
            *(uint4*)&Ws[tid >> 2][(tid & 3) * 8]        = pv0;
            *(uint4*)&Ws[64 + (tid >> 2)][(tid & 3) * 8] = pv1;
        }
        __syncthreads();
    }

    float bi0 = b1[n0 + lrow], bi1 = b1[n0 + 16 + lrow];
    #pragma unroll
    for (int mb = 0; mb < 4; ++mb)
        #pragma unroll
        for (int q = 0; q < 4; ++q) {
            int gr = row0 + mb * 16 + lk8 * 4 + q;
            if (gr < N) {
                float v0 = acc[mb][0][q] + bi0;
                float v1 = acc[mb][1][q] + bi1;
                h[(size_t)gr * NCH + n0 + lrow]       = v0;
                h[(size_t)gr * NCH + n0 + 16 + lrow]  = v1;
                h2[(size_t)gr * NCH + n0 + lrow]      = (_Float16)v0;
                h2[(size_t)gr * NCH + n0 + 16 + lrow] = (_Float16)v1;
            }
        }
}

// ============ Kernel 2 (fast): MFMA edge MLP, single-buffer Ws + reg prefetch
__global__ __launch_bounds__(256, 3) void k_edges_mfma(
    const int* __restrict__ ei, const float* __restrict__ eattr,
    const float* __restrict__ xpos, const _Float16* __restrict__ h2,
    float* h,   // atomic target (aliases d_out)
    const _Float16* __restrict__ w1c, const _Float16* __restrict__ w2c,
    const _Float16* __restrict__ w3c,
    const float* __restrict__ mb1, const float* __restrict__ mb2,
    const float* __restrict__ mb3, int E)
{
    __shared__ __align__(16) _Float16 As[TE][AP];   // 37888 B
    __shared__ __align__(16) _Float16 Ws[128][WP];  // 10240 B
    __shared__ int srcS[TE], dstS[TE];
    __shared__ float rS[TE];

    const int tid  = threadIdx.x;
    const int e0   = blockIdx.x * TE;
    const int lane = tid & 63;
    const int w    = tid >> 6;
    const int lrow = lane & 15;
    const int lk8  = lane >> 4;
    const int n0   = w * 32;

    // prefetch W chunk 0 immediately (latency hides under phase 1/2)
    const uint4* wsrc = (const uint4*)w1c;
    uint4 pv0 = wsrc[tid], pv1 = wsrc[tid + 256];

    // ---- phase 1: per-edge metadata + distance (64 threads)
    if (tid < TE) {
        int e = e0 + tid;
        int s = 0, d = -1;
        float r = 0.f;
        if (e < E) {
            s = ei[e];
            d = ei[E + e];
            float dx = xpos[d * 3 + 0] - xpos[s * 3 + 0];
            float dy = xpos[d * 3 + 1] - xpos[s * 3 + 1];
            float dz = xpos[d * 3 + 2] - xpos[s * 3 + 2];
            r = sqrtf(dx * dx + dy * dy + dz * dz);
        }
        srcS[tid] = s;
        dstS[tid] = d;
        rS[tid]   = r;
    }
    __syncthreads();

    // ---- phase 2a: RBF sin/cos, parallel over all 256 threads (4 pairs each)
    {
        int e  = tid >> 2;
        int i0 = tid & 3;
        float r = rS[e];
        #pragma unroll
        for (int u = 0; u < 4; ++u) {
            int i = i0 * 4 + u;
            float om = 10.f * exp2f(7.0f - 0.875f * (float)i);  // 10*128^(1-i/8)
            float f = r * om, sv, cv;
            sincosf(f, &sv, &cv);
            As[e][i]      = (_Float16)sv;
            As[e][16 + i] = (_Float16)cv;
        }
    }
    // ---- phase 2b: stage edge_attr (f32->f16) and h2[src] (f16 copy)
    #pragma unroll
    for (int t = 0; t < 8; ++t) {
        int idx = tid + t * 256;
        int row = idx >> 5, f4 = idx & 31;
        int e = e0 + row;
        float4 va = {0.f, 0.f, 0.f, 0.f};
        if (e < E) va = *(const float4*)(eattr + (size_t)e * NCH + f4 * 4);
        half4 pa = {(_Float16)va.x, (_Float16)va.y, (_Float16)va.z, (_Float16)va.w};
        *(half4*)&As[row][32 + f4 * 4] = pa;
    }
    #pragma unroll
    for (int t = 0; t < 4; ++t) {
        int idx = tid + t * 256;
        int row = idx >> 4, c8 = idx & 15;
        int e = e0 + row;
        uint4 v = {0u, 0u, 0u, 0u};
        if (e < E) v = *(const uint4*)(h2 + (size_t)srcS[row] * NCH + c8 * 8);
        *(uint4*)&As[row][160 + c8 * 8] = v;
    }
    // write W chunk 0
    *(uint4*)&Ws[tid >> 2][(tid & 3) * 8]        = pv0;
    *(uint4*)&Ws[64 + (tid >> 2)][(tid & 3) * 8] = pv1;
    __syncthreads();

    f32x4 acc[4][2];
    #pragma unroll
    for (int mb = 0; mb < 4; ++mb)
        #pragma unroll
        for (int nf = 0; nf < 2; ++nf) acc[mb][nf] = (f32x4){0.f, 0.f, 0.f, 0.f};

    auto epi = [&](const float* __restrict__ mbv) {
        // between barriers: all waves done reading As/Ws for current chunk.
        float bi0 = mbv[n0 + lrow], bi1 = mbv[n0 + 16 + lrow];
        #pragma unroll
        for (int mb = 0; mb < 4; ++mb)
            #pragma unroll
            for (int nf = 0; nf < 2; ++nf) {
                float bb = nf ? bi1 : bi0;
                #pragma unroll
                for (int q = 0; q < 4; ++q) {
                    float g = gelu_exact(acc[mb][nf][q] + bb);
                    As[mb * 16 + lk8 * 4 + q][n0 + nf * 16 + lrow] = (_Float16)g;
                }
                acc[mb][nf] = (f32x4){0.f, 0.f, 0.f, 0.f};
            }
    };

    // ---- main loop: 17 K-chunks (9 layer1, 4 layer2, 4 layer3)
    for (int i = 0; i < 17; ++i) {
        if (i < 16) {
            int j = i + 1;
            const _Float16* nw = (j < 9)  ? (w1c + j * 4096)
                               : (j < 13) ? (w2c + (j - 9) * 4096)
                                          : (w3c + (j - 13) * 4096);
            const uint4* s = (const uint4*)nw;
            pv0 = s[tid]; pv1 = s[tid + 256];
        }
        const int lc = (i < 9) ? i : (i < 13) ? (i - 9) : (i - 13);

        half8 av[4], bv[2];
        #pragma unroll
        for (int mb = 0; mb < 4; ++mb)
            av[mb] = *(const half8*)&As[mb * 16 + lrow][lc * 32 + lk8 * 8];
        #pragma unroll
        for (int nf = 0; nf < 2; ++nf)
            bv[nf] = *(const half8*)&Ws[n0 + nf * 16 + lrow][lk8 * 8];
        #pragma unroll
        for (int mb = 0; mb < 4; ++mb)
            #pragma unroll
            for (int nf = 0; nf < 2; ++nf)
                acc[mb][nf] = __builtin_amdgcn_mfma_f32_16x16x32_f16(
                    av[mb], bv[nf], acc[mb][nf], 0, 0, 0);

        __syncthreads();   // done reading As & Ws for chunk i
        if (i == 8)       epi(mb1);
        else if (i == 12) epi(mb2);
        if (i < 16) {
            *(uint4*)&Ws[tid >> 2][(tid & 3) * 8]        = pv0;
            *(uint4*)&Ws[64 + (tid >> 2)][(tid & 3) * 8] = pv1;
        }
        __syncthreads();   // As/Ws writes visible
    }

    // ---- final: bias + scatter-add into h
    {
        float bi0 = mb3[n0 + lrow], bi1 = mb3[n0 + 16 + lrow];
        #pragma unroll
        for (int mb = 0; mb < 4; ++mb)
            #pragma unroll
            for (int q = 0; q < 4; ++q) {
                int el = mb * 16 + lk8 * 4 + q;
                int d = dstS[el];
                if (d >= 0) {
                    atomicAdd(h + (size_t)d * NCH + n0 + lrow,      acc[mb][0][q] + bi0);
                    atomicAdd(h + (size_t)d * NCH + n0 + 16 + lrow, acc[mb][1][q] + bi1);
                }
            }
    }
}

// ============ Kernel 3 (fast): out = relu(h@w2+b2)@w3+b3 via MFMA, in-place
__global__ __launch_bounds__(256, 4) void k_out_mfma(
    const float* h, const _Float16* __restrict__ w2c,
    const float* __restrict__ b2, const _Float16* __restrict__ w3c,
    const float* __restrict__ b3, float* out, int N)
{
    __shared__ __align__(16) _Float16 Xs[64][XP];
    __shared__ __align__(16) _Float16 Ws[128][WP];

    const int tid  = threadIdx.x;
    const int row0 = blockIdx.x * 64;
    const int lane = tid & 63;
    const int w    = tid >> 6;
    const int lrow = lane & 15;
    const int lk8  = lane >> 4;
    const int n0   = w * 32;

    const uint4* wsrc = (const uint4*)w2c;
    uint4 pv0 = wsrc[tid], pv1 = wsrc[tid + 256];

    #pragma unroll
    for (int t = 0; t < 8; ++t) {
        int idx = tid + t * 256;
        int r = idx >> 5, f4 = idx & 31;
        int gr = row0 + r;
        float4 v = {0.f, 0.f, 0.f, 0.f};
        if (gr < N) v = *(const float4*)(h + (size_t)gr * NCH + f4 * 4);
        half4 p = {(_Float16)v.x, (_Float16)v.y, (_Float16)v.z, (_Float16)v.w};
        *(half4*)&Xs[r][f4 * 4] = p;
    }
    *(uint4*)&Ws[tid >> 2][(tid & 3) * 8]        = pv0;
    *(uint4*)&Ws[64 + (tid >> 2)][(tid & 3) * 8] = pv1;
    __syncthreads();

    f32x4 acc[4][2];
    #pragma unroll
    for (int mb = 0; mb < 4; ++mb)
        #pragma unroll
        for (int nf = 0; nf < 2; ++nf) acc[mb][nf] = (f32x4){0.f, 0.f, 0.f, 0.f};

    for (int i = 0; i < 8; ++i) {
        if (i < 7) {
            int j = i + 1;
            const _Float16* nw = (j < 4) ? (w2c + j * 4096) : (w3c + (j - 4) * 4096);
            const uint4* s = (const uint4*)nw;
            pv0 = s[tid]; pv1 = s[tid + 256];
        }
        const int lc = i & 3;
        half8 av[4], bv[2];
        #pragma unroll
        for (int mb = 0; mb < 4; ++mb)
            av[mb] = *(const half8*)&Xs[mb * 16 + lrow][lc * 32 + lk8 * 8];
        #pragma unroll
        for (int nf = 0; nf < 2; ++nf)
            bv[nf] = *(const half8*)&Ws[n0 + nf * 16 + lrow][lk8 * 8];
        #pragma unroll
        for (int mb = 0; mb < 4; ++mb)
            #pragma unroll
            for (int nf = 0; nf < 2; ++nf)
                acc[mb][nf] = __builtin_amdgcn_mfma_f32_16x16x32_f16(
                    av[mb], bv[nf], acc[mb][nf], 0, 0, 0);

        __syncthreads();
        if (i == 3) {   // relu epilogue -> Xs (in place, all layer-1 reads done)
            float bi0 = b2[n0 + lrow], bi1 = b2[n0 + 16 + lrow];
            #pragma unroll
            for (int mb = 0; mb < 4; ++mb)
                #pragma unroll
                for (int nf = 0; nf < 2; ++nf) {
                    float bb = nf ? bi1 : bi0;
                    #pragma unroll
                    for (int q = 0; q < 4; ++q) {
                        float g = fmaxf(acc[mb][nf][q] + bb, 0.f);
                        Xs[mb * 16 + lk8 * 4 + q][n0 + nf * 16 + lrow] = (_Float16)g;
                    }
                    acc[mb][nf] = (f32x4){0.f, 0.f, 0.f, 0.f};
                }
        }
        if (i < 7) {
            *(uint4*)&Ws[tid >> 2][(tid & 3) * 8]        = pv0;
            *(uint4*)&Ws[64 + (tid >> 2)][(tid & 3) * 8] = pv1;
        }
        __syncthreads();
    }

    float bi0 = b3[n0 + lrow], bi1 = b3[n0 + 16 + lrow];
    #pragma unroll
    for (int mb = 0; mb < 4; ++mb)
        #pragma unroll
        for (int q = 0; q < 4; ++q) {
            int gr = row0 + mb * 16 + lk8 * 4 + q;
            if (gr < N) {
                out[(size_t)gr * NCH + n0 + lrow]      = acc[mb][0][q] + bi0;
                out[(size_t)gr * NCH + n0 + 16 + lrow] = acc[mb][1][q] + bi1;
            }
        }
}

// ==================== fp32 fallback path (round-1, proven) ====================
__global__ __launch_bounds__(256) void k_atomwise1(
    const float* __restrict__ x, const float* __restrict__ w1,
    const float* __restrict__ b1, float* __restrict__ h,
    float* __restrict__ h2, int N)
{
    __shared__ float xs[16][NCH];
    const int row0 = blockIdx.x * 16;
    const int tid = threadIdx.x;
    #pragma unroll
    for (int t = 0; t < 8; ++t) {
        int idx = tid + t * 256;
        int r = idx >> 7, c = idx & 127;
        int gr = row0 + r;
        xs[r][c] = (gr < N) ? x[(size_t)gr * NCH + c] : 0.f;
    }
    __syncthreads();
    const int j = tid & 127;
    const int rg = tid >> 7;
    float acc[8];
    #pragma unroll
    for (int i = 0; i < 8; ++i) acc[i] = 0.f;
    for (int k = 0; k < NCH; ++k) {
        float wv = w1[(size_t)k * NCH + j];
        #pragma unroll
        for (int i = 0; i < 8; ++i)
            acc[i] = fmaf(xs[rg * 8 + i][k], wv, acc[i]);
    }
    float bv = b1[j];
    #pragma unroll
    for (int i = 0; i < 8; ++i) {
        int gr = row0 + rg * 8 + i;
        if (gr < N) {
            float v = acc[i] + bv;
            h[(size_t)gr * NCH + j]  = v;
            h2[(size_t)gr * NCH + j] = v;
        }
    }
}

__global__ __launch_bounds__(256) void k_edges_f32(
    const int* __restrict__ ei, const float* __restrict__ eattr,
    const float* __restrict__ xpos, const float* __restrict__ h,
    const float* __restrict__ mw1, const float* __restrict__ mb1,
    const float* __restrict__ mw2, const float* __restrict__ mb2,
    const float* __restrict__ mw3, const float* __restrict__ mb3,
    float* __restrict__ agg, int E)
{
    __shared__ __align__(16) float Asf[TE][292];
    __shared__ float Wsf[32][NCH];
    __shared__ int srcS[TE];
    __shared__ int dstS[TE];
    const int tid = threadIdx.x;
    const int e0 = blockIdx.x * TE;
    if (tid < TE) {
        int e = e0 + tid;
        int s = 0, d = -1;
        float r = 0.f;
        if (e < E) {
            s = ei[e]; d = ei[E + e];
            float dx = xpos[d * 3 + 0] - xpos[s * 3 + 0];
            float dy = xpos[d * 3 + 1] - xpos[s * 3 + 1];
            float dz = xpos[d * 3 + 2] - xpos[s * 3 + 2];
            r = sqrtf(dx * dx + dy * dy + dz * dz);
        }
        srcS[tid] = s; dstS[tid] = d;
        #pragma unroll
        for (int i = 0; i < 16; ++i) {
            float om = 10.f * exp2f(7.0f - 0.875f * (float)i);
            float f = r * om;
            Asf[tid][i] = sinf(f); Asf[tid][16 + i] = cosf(f);
        }
    }
    __syncthreads();
    {
        const int half = tid >> 7;
        const int c = tid & 127;
        for (int ee = 0; ee < TE; ee += 2) {
            int le = ee + half;
            int e = e0 + le;
            if (e < E) {
                Asf[le][32 + c]  = eattr[(size_t)e * NCH + c];
                Asf[le][160 + c] = h[(size_t)srcS[le] * NCH + c];
            } else { Asf[le][32 + c] = 0.f; Asf[le][160 + c] = 0.f; }
        }
    }
    const int jl = tid & 31;
    const int g  = tid >> 5;
    float acc[8][4];
    auto run_layer = [&](const float* __restrict__ Wg, int K) {
        #pragma unroll
        for (int i = 0; i < 8; ++i)
            #pragma unroll
            for (int c = 0; c < 4; ++c) acc[i][c] = 0.f;
        for (int k0 = 0; k0 < K; k0 += 32) {
            __syncthreads();
            #pragma unroll
            for (int t = 0; t < 16; ++t) {
                int idx = tid + t * 256;
                Wsf[idx >> 7][idx & 127] =
                    Wg[(size_t)(k0 + (idx >> 7)) * NCH + (idx & 127)];
            }
            __syncthreads();
            #pragma unroll
            for (int kk = 0; kk < 32; kk += 4) {
                float4 a[8];
                #pragma unroll
                for (int i = 0; i < 8; ++i)
                    a[i] = *reinterpret_cast<const float4*>(&Asf[g * 8 + i][k0 + kk]);
                #pragma unroll
                for (int u = 0; u < 4; ++u) {
                    float w0 = Wsf[kk + u][jl];
                    float w1v = Wsf[kk + u][jl + 32];
                    float w2v = Wsf[kk + u][jl + 64];
                    float w3v = Wsf[kk + u][jl + 96];
                    #pragma unroll
                    for (int i = 0; i < 8; ++i) {
                        float avv = (&a[i].x)[u];
                        acc[i][0] = fmaf(avv, w0, acc[i][0]);
                        acc[i][1] = fmaf(avv, w1v, acc[i][1]);
                        acc[i][2] = fmaf(avv, w2v, acc[i][2]);
                        acc[i][3] = fmaf(avv, w3v, acc[i][3]);
                    }
                }
            }
        }
    };
    run_layer(mw1, 288);
    #pragma unroll
    for (int i = 0; i < 8; ++i)
        #pragma unroll
        for (int c = 0; c < 4; ++c) {
            int j = jl + 32 * c;
            Asf[g * 8 + i][j] = gelu_exact(acc[i][c] + mb1[j]);
        }
    run_layer(mw2, 128);
    #pragma unroll
    for (int i = 0; i < 8; ++i)
        #pragma unroll
        for (int c = 0; c < 4; ++c) {
            int j = jl + 32 * c;
            Asf[g * 8 + i][j] = gelu_exact(acc[i][c] + mb2[j]);
        }
    run_layer(mw3, 128);
    #pragma unroll
    for (int i = 0; i < 8; ++i) {
        int d = dstS[g * 8 + i];
        if (d >= 0) {
            #pragma unroll
            for (int c = 0; c < 4; ++c) {
                int j = jl + 32 * c;
                atomicAdd(&agg[(size_t)d * NCH + j], acc[i][c] + mb3[j]);
            }
        }
    }
}

__global__ __launch_bounds__(256) void k_out(
    const float* h, const float* aggOpt,
    const float* __restrict__ w2, const float* __restrict__ b2,
    const float* __restrict__ w3, const float* __restrict__ b3,
    float* out, int N)
{
    __shared__ float hs[16][NCH];
    __shared__ float ts[16][NCH];
    const int row0 = blockIdx.x * 16;
    const int tid = threadIdx.x;
    #pragma unroll
    for (int t = 0; t < 8; ++t) {
        int idx = tid + t * 256;
        int r = idx >> 7, c = idx & 127;
        int gr = row0 + r;
        float v = 0.f;
        if (gr < N) {
            v = h[(size_t)gr * NCH + c];
            if (aggOpt) v += aggOpt[(size_t)gr * NCH + c];
        }
        hs[r][c] = v;
    }
    __syncthreads();
    const int j = tid & 127;
    const int rg = tid >> 7;
    float acc[8];
    #pragma unroll
    for (int i = 0; i < 8; ++i) acc[i] = 0.f;
    for (int k = 0; k < NCH; ++k) {
        float wv = w2[(size_t)k * NCH + j];
        #pragma unroll
        for (int i = 0; i < 8; ++i)
            acc[i] = fmaf(hs[rg * 8 + i][k], wv, acc[i]);
    }
    float bv = b2[j];
    #pragma unroll
    for (int i = 0; i < 8; ++i)
        ts[rg * 8 + i][j] = fmaxf(acc[i] + bv, 0.f);
    __syncthreads();
    float acc2[8];
    #pragma unroll
    for (int i = 0; i < 8; ++i) acc2[i] = 0.f;
    for (int k = 0; k < NCH; ++k) {
        float wv = w3[(size_t)k * NCH + j];
        #pragma unroll
        for (int i = 0; i < 8; ++i)
            acc2[i] = fmaf(ts[rg * 8 + i][k], wv, acc2[i]);
    }
    float b3v = b3[j];
    #pragma unroll
    for (int i = 0; i < 8; ++i) {
        int gr = row0 + rg * 8 + i;
        if (gr < N) out[(size_t)gr * NCH + j] = acc2[i] + b3v;
    }
}

extern "C" void kernel_launch(void* const* d_in, const int* in_sizes, int n_in,
                              void* d_out, int out_size, void* d_ws, size_t ws_size,
                              hipStream_t stream)
{
    const float* x     = (const float*)d_in[0];
    const int*   ei    = (const int*)d_in[1];
    const float* eattr = (const float*)d_in[2];
    const float* xpos  = (const float*)d_in[3];
    const float* w1    = (const float*)d_in[4];
    const float* b1    = (const float*)d_in[5];
    const float* mw1   = (const float*)d_in[6];
    const float* mb1   = (const float*)d_in[7];
    const float* mw2   = (const float*)d_in[8];
    const float* mb2   = (const float*)d_in[9];
    const float* mw3   = (const float*)d_in[10];
    const float* mb3   = (const float*)d_in[11];
    const float* w2    = (const float*)d_in[12];
    const float* b2    = (const float*)d_in[13];
    const float* w3    = (const float*)d_in[14];
    const float* b3    = (const float*)d_in[15];

    const int N = in_sizes[0] / NCH;
    const int E = in_sizes[1] / 2;

    float* h = (float*)d_out;

    const size_t h2_bytes = (size_t)N * NCH * sizeof(_Float16);
    const size_t wchunks  = 9 + 4 + 4 + 4 + 4 + 4;   // mw1,mw2,mw3,w1,w2,w3
    const size_t wbytes   = wchunks * 4096 * sizeof(_Float16);
    const bool fast = ws_size >= h2_bytes + wbytes;

    if (fast) {
        _Float16* h2   = (_Float16*)d_ws;
        _Float16* w1c  = (_Float16*)((char*)d_ws + h2_bytes);
        _Float16* w2c  = w1c + 9 * 4096;
        _Float16* w3c  = w2c + 4 * 4096;
        _Float16* aw1c = w3c + 4 * 4096;
        _Float16* o2c  = aw1c + 4 * 4096;
        _Float16* o3c  = o2c + 4 * 4096;
        k_prep<<<144, 256, 0, stream>>>(mw1, w1c, 288 * 128);
        k_prep<<<64, 256, 0, stream>>>(mw2, w2c, 128 * 128);
        k_prep<<<64, 256, 0, stream>>>(mw3, w3c, 128 * 128);
        k_prep<<<64, 256, 0, stream>>>(w1, aw1c, 128 * 128);
        k_prep<<<64, 256, 0, stream>>>(w2, o2c, 128 * 128);
        k_prep<<<64, 256, 0, stream>>>(w3, o3c, 128 * 128);
        const int nb = (N + 63) / 64;
        k_aw1_mfma<<<nb, 256, 0, stream>>>(x, aw1c, b1, h, h2, N);
        k_edges_mfma<<<(E + TE - 1) / TE, 256, 0, stream>>>(
            ei, eattr, xpos, h2, h, w1c, w2c, w3c, mb1, mb2, mb3, E);
        k_out_mfma<<<nb, 256, 0, stream>>>(h, o2c, b2, o3c, b3, (float*)d_out, N);
    } else {
        float* agg = (float*)d_ws;
        k_atomwise1<<<(N + 15) / 16, 256, 0, stream>>>(x, w1, b1, h, agg, N);
        hipMemsetAsync(agg, 0, (size_t)N * NCH * sizeof(float), stream);
        k_edges_f32<<<(E + TE - 1) / TE, 256, 0, stream>>>(
            ei, eattr, xpos, h, mw1, mb1, mw2, mb2, mw3, mb3, agg, E);
        k_out<<<(N + 15) / 16, 256, 0, stream>>>(h, agg, w2, b2, w3, b3,
                                                 (float*)d_out, N);
    }
}

// Round 4
// 547.387 us; speedup vs baseline: 9.0899x; 1.1662x over previous
//
#include <hip/hip_runtime.h>
#include <math.h>

#define NCH 128
#define TE 64
#define AP 296   // msg_in row pad (f16): 592B row = 148 words, gcd(148,32)=4 -> uniform 8 words/bank on b128
#define WP 40    // (fallback kernels only)
#define XP 136   // node-tile row pad (f16)

typedef __attribute__((ext_vector_type(8))) _Float16 half8;
typedef __attribute__((ext_vector_type(4))) _Float16 half4;
typedef __attribute__((ext_vector_type(4))) float f32x4;

__device__ __forceinline__ float gelu_exact(float v) {
    return 0.5f * v * (1.0f + erff(v * 0.70710678118654752f));
}

// ============ prep A: W[K][128] fp32 -> k-chunked transposed f16 [K/32][128][32]
// (used by k_aw1_mfma / k_out_mfma LDS-staged path)
__global__ __launch_bounds__(256) void k_prep(const float* __restrict__ W,
                                              _Float16* __restrict__ out, int total) {
    int idx = blockIdx.x * 256 + threadIdx.x;
    if (idx >= total) return;
    int k = idx >> 7, n = idx & 127;
    out[(size_t)(k >> 5) * 4096 + n * 32 + (k & 31)] = (_Float16)W[idx];
}

// ============ prep B: W[K][128] fp32 -> per-lane MFMA fragment order
// layout: [chunk][wave(4)][nf(2)][lane(64)][8 f16]; one thread per fragment-slot
__global__ __launch_bounds__(256) void k_prep_frag(const float* __restrict__ W,
                                                   _Float16* __restrict__ out,
                                                   int nchunks) {
    int idx = blockIdx.x * 256 + threadIdx.x;
    if (idx >= nchunks * 512) return;
    int c    = idx >> 9;
    int r    = idx & 511;
    int wv   = r >> 7;
    int nf   = (r >> 6) & 1;
    int lane = r & 63;
    int n  = wv * 32 + nf * 16 + (lane & 15);
    int k0 = c * 32 + (lane >> 4) * 8;
    half8 v;
    #pragma unroll
    for (int j = 0; j < 8; ++j) v[j] = (_Float16)W[(size_t)(k0 + j) * NCH + n];
    *(half8*)(out + (size_t)idx * 8) = v;
}

// ============ Kernel 1 (fast): h = x@w1+b1 via MFMA -> h fp32 (d_out) + h2 f16
__global__ __launch_bounds__(256, 4) void k_aw1_mfma(
    const float* __restrict__ x, const _Float16* __restrict__ wc,
    const float* __restrict__ b1, float* __restrict__ h,
    _Float16* __restrict__ h2, int N)
{
    __shared__ __align__(16) _Float16 Xs[64][XP];
    __shared__ __align__(16) _Float16 Ws[128][WP];

    const int tid  = threadIdx.x;
    const int row0 = blockIdx.x * 64;
    const int lane = tid & 63;
    const int w    = tid >> 6;
    const int lrow = lane & 15;
    const int lk8  = lane >> 4;
    const int n0   = w * 32;

    const uint4* wsrc = (const uint4*)wc;
    uint4 pv0 = wsrc[tid], pv1 = wsrc[tid + 256];

    #pragma unroll
    for (int t = 0; t < 8; ++t) {
        int idx = tid + t * 256;
        int r = idx >> 5, f4 = idx & 31;
        int gr = row0 + r;
        float4 v = {0.f, 0.f, 0.f, 0.f};
        if (gr < N) v = *(const float4*)(x + (size_t)gr * NCH + f4 * 4);
        half4 p = {(_Float16)v.x, (_Float16)v.y, (_Float16)v.z, (_Float16)v.w};
        *(half4*)&Xs[r][f4 * 4] = p;
    }
    *(uint4*)&Ws[tid >> 2][(tid & 3) * 8]        = pv0;
    *(uint4*)&Ws[64 + (tid >> 2)][(tid & 3) * 8] = pv1;
    __syncthreads();

    f32x4 acc[4][2];
    #pragma unroll
    for (int mb = 0; mb < 4; ++mb)
        #pragma unroll
        for (int nf = 0; nf < 2; ++nf) acc[mb][nf] = (f32x4){0.f, 0.f, 0.f, 0.f};

    for (int i = 0; i < 4; ++i) {
        if (i < 3) {
            const uint4* s = (const uint4*)(wc + (i + 1) * 4096);
            pv0 = s[tid]; pv1 = s[tid + 256];
        }
        half8 av[4], bv[2];
        #pragma unroll
        for (int mb = 0; mb < 4; ++mb)
            av[mb] = *(const half8*)&Xs[mb * 16 + lrow][i * 32 + lk8 * 8];
        #pragma unroll
        for (int nf = 0; nf < 2; ++nf)
            bv[nf] = *(const half8*)&Ws[n0 + nf * 16 + lrow][lk8 * 8];
        #pragma unroll
        for (int mb = 0; mb < 4; ++mb)
            #pragma unroll
            for (int nf = 0; nf < 2; ++nf)
                acc[mb][nf] = __builtin_amdgcn_mfma_f32_16x16x32_f16(
                    av[mb], bv[nf], acc[mb][nf], 0, 0, 0);
        __syncthreads();
        if (i < 3) {
            *(uint4*)&Ws[tid >> 2][(tid & 3) * 8]        = pv0;
            *(uint4*)&Ws[64 + (tid >> 2)][(tid & 3) * 8] = pv1;
        }
        __syncthreads();
    }

    float bi0 = b1[n0 + lrow], bi1 = b1[n0 + 16 + lrow];
    #pragma unroll
    for (int mb = 0; mb < 4; ++mb)
        #pragma unroll
        for (int q = 0; q < 4; ++q) {
            int gr = row0 + mb * 16 + lk8 * 4 + q;
            if (gr < N) {
                float v0 = acc[mb][0][q] + bi0;
                float v1 = acc[mb][1][q] + bi1;
                h[(size_t)gr * NCH + n0 + lrow]       = v0;
                h[(size_t)gr * NCH + n0 + 16 + lrow]  = v1;
                h2[(size_t)gr * NCH + n0 + lrow]      = (_Float16)v0;
                h2[(size_t)gr * NCH + n0 + 16 + lrow] = (_Float16)v1;
            }
        }
}

// ============ Kernel 2 (fast): edge MLP — B streamed from L2 in fragment order
__global__ __launch_bounds__(256, 4) void k_edges_mfma(
    const int* __restrict__ ei, const float* __restrict__ eattr,
    const float* __restrict__ xpos, const _Float16* __restrict__ h2,
    float* h,   // atomic target (aliases d_out)
    const _Float16* __restrict__ wf,   // fragment-packed mw1|mw2|mw3 (17 chunks)
    const float* __restrict__ mb1, const float* __restrict__ mb2,
    const float* __restrict__ mb3, int E)
{
    __shared__ __align__(16) _Float16 As[TE][AP];   // 37888 B (only LDS tile)

    const int tid  = threadIdx.x;
    const int e0   = blockIdx.x * TE;
    const int lane = tid & 63;
    const int w    = tid >> 6;
    const int lrow = lane & 15;
    const int lk8  = lane >> 4;
    const int n0   = w * 32;

    // ---- T14 stage: issue ALL global loads first, compute trig under them
    float4 ea[8];
    #pragma unroll
    for (int t = 0; t < 8; ++t) {
        int idx = tid + t * 256;
        int e = e0 + (idx >> 5);
        ea[t] = (e < E) ? *(const float4*)(eattr + (size_t)e * NCH + (idx & 31) * 4)
                        : (float4){0.f, 0.f, 0.f, 0.f};
    }
    uint4 hv[4];
    #pragma unroll
    for (int t = 0; t < 4; ++t) {
        int idx = tid + t * 256;
        int e = e0 + (idx >> 4);
        int s = (e < E) ? ei[e] : 0;
        hv[t] = *(const uint4*)(h2 + (size_t)s * NCH + (idx & 15) * 8);
    }

    // trig: 4 threads per edge, 4 (sin,cos) pairs each — VALU under load latency
    {
        int le = tid >> 2, i0 = tid & 3;
        int ge = e0 + le;
        float r = 0.f;
        if (ge < E) {
            int s = ei[ge], d = ei[E + ge];
            float dx = xpos[d * 3 + 0] - xpos[s * 3 + 0];
            float dy = xpos[d * 3 + 1] - xpos[s * 3 + 1];
            float dz = xpos[d * 3 + 2] - xpos[s * 3 + 2];
            r = sqrtf(dx * dx + dy * dy + dz * dz);
        }
        #pragma unroll
        for (int u = 0; u < 4; ++u) {
            int i = i0 * 4 + u;
            float om = 10.f * exp2f(7.0f - 0.875f * (float)i);  // 10*128^(1-i/8)
            float f = r * om, sv, cv;
            sincosf(f, &sv, &cv);
            As[le][i]      = (_Float16)sv;
            As[le][16 + i] = (_Float16)cv;
        }
    }
    // write-late: convert eattr, copy h2
    #pragma unroll
    for (int t = 0; t < 8; ++t) {
        int idx = tid + t * 256;
        half4 p = {(_Float16)ea[t].x, (_Float16)ea[t].y,
                   (_Float16)ea[t].z, (_Float16)ea[t].w};
        *(half4*)&As[idx >> 5][32 + (idx & 31) * 4] = p;
    }
    #pragma unroll
    for (int t = 0; t < 4; ++t) {
        int idx = tid + t * 256;
        *(uint4*)&As[idx >> 4][160 + (idx & 15) * 8] = hv[t];
    }
    __syncthreads();

    f32x4 acc[4][2];
    #pragma unroll
    for (int mb = 0; mb < 4; ++mb)
        #pragma unroll
        for (int nf = 0; nf < 2; ++nf) acc[mb][nf] = (f32x4){0.f, 0.f, 0.f, 0.f};

    // B fragment: wf in half8 units — chunk stride 512, wave 128, nf 64, lane 1
    const half8* bp = (const half8*)wf;
    const int bbase = w * 128 + lane;

    auto epi = [&](const float* __restrict__ mbv) {
        float bi0 = mbv[n0 + lrow], bi1 = mbv[n0 + 16 + lrow];
        #pragma unroll
        for (int mb = 0; mb < 4; ++mb)
            #pragma unroll
            for (int nf = 0; nf < 2; ++nf) {
                float bb = nf ? bi1 : bi0;
                #pragma unroll
                for (int q = 0; q < 4; ++q) {
                    float g = gelu_exact(acc[mb][nf][q] + bb);
                    As[mb * 16 + lk8 * 4 + q][n0 + nf * 16 + lrow] = (_Float16)g;
                }
                acc[mb][nf] = (f32x4){0.f, 0.f, 0.f, 0.f};
            }
    };

    // ---- layer 1: 9 chunks, barrier-free
    #pragma unroll
    for (int c = 0; c < 9; ++c) {
        half8 b0 = bp[(size_t)c * 512 + bbase];
        half8 b1 = bp[(size_t)c * 512 + bbase + 64];
        #pragma unroll
        for (int mb = 0; mb < 4; ++mb) {
            half8 av = *(const half8*)&As[mb * 16 + lrow][c * 32 + lk8 * 8];
            acc[mb][0] = __builtin_amdgcn_mfma_f32_16x16x32_f16(av, b0, acc[mb][0], 0, 0, 0);
            acc[mb][1] = __builtin_amdgcn_mfma_f32_16x16x32_f16(av, b1, acc[mb][1], 0, 0, 0);
        }
    }
    __syncthreads();        // all layer-1 A-reads done
    epi(mb1);
    __syncthreads();        // gelu writes visible

    // ---- layer 2: 4 chunks
    #pragma unroll
    for (int c = 0; c < 4; ++c) {
        half8 b0 = bp[(size_t)(9 + c) * 512 + bbase];
        half8 b1 = bp[(size_t)(9 + c) * 512 + bbase + 64];
        #pragma unroll
        for (int mb = 0; mb < 4; ++mb) {
            half8 av = *(const half8*)&As[mb * 16 + lrow][c * 32 + lk8 * 8];
            acc[mb][0] = __builtin_amdgcn_mfma_f32_16x16x32_f16(av, b0, acc[mb][0], 0, 0, 0);
            acc[mb][1] = __builtin_amdgcn_mfma_f32_16x16x32_f16(av, b1, acc[mb][1], 0, 0, 0);
        }
    }
    __syncthreads();
    epi(mb2);
    __syncthreads();

    // ---- layer 3: 4 chunks
    #pragma unroll
    for (int c = 0; c < 4; ++c) {
        half8 b0 = bp[(size_t)(13 + c) * 512 + bbase];
        half8 b1 = bp[(size_t)(13 + c) * 512 + bbase + 64];
        #pragma unroll
        for (int mb = 0; mb < 4; ++mb) {
            half8 av = *(const half8*)&As[mb * 16 + lrow][c * 32 + lk8 * 8];
            acc[mb][0] = __builtin_amdgcn_mfma_f32_16x16x32_f16(av, b0, acc[mb][0], 0, 0, 0);
            acc[mb][1] = __builtin_amdgcn_mfma_f32_16x16x32_f16(av, b1, acc[mb][1], 0, 0, 0);
        }
    }

    // ---- bias + scatter-add into h
    {
        float bi0 = mb3[n0 + lrow], bi1 = mb3[n0 + 16 + lrow];
        #pragma unroll
        for (int mb = 0; mb < 4; ++mb)
            #pragma unroll
            for (int q = 0; q < 4; ++q) {
                int e = e0 + mb * 16 + lk8 * 4 + q;
                if (e < E) {
                    int d = ei[E + e];
                    atomicAdd(h + (size_t)d * NCH + n0 + lrow,      acc[mb][0][q] + bi0);
                    atomicAdd(h + (size_t)d * NCH + n0 + 16 + lrow, acc[mb][1][q] + bi1);
                }
            }
    }
}

// ============ Kernel 3 (fast): out = relu(h@w2+b2)@w3+b3 via MFMA, in-place
__global__ __launch_bounds__(256, 4) void k_out_mfma(
    const float* h, const _Float16* __restrict__ w2c,
    const float* __restrict__ b2, const _Float16* __restrict__ w3c,
    const float* __restrict__ b3, float* out, int N)
{
    __shared__ __align__(16) _Float16 Xs[64][XP];
    __shared__ __align__(16) _Float16 Ws[128][WP];

    const int tid  = threadIdx.x;
    const int row0 = blockIdx.x * 64;
    const int lane = tid & 63;
    const int w    = tid >> 6;
    const int lrow = lane & 15;
    const int lk8  = lane >> 4;
    const int n0   = w * 32;

    const uint4* wsrc = (const uint4*)w2c;
    uint4 pv0 = wsrc[tid], pv1 = wsrc[tid + 256];

    #pragma unroll
    for (int t = 0; t < 8; ++t) {
        int idx = tid + t * 256;
        int r = idx >> 5, f4 = idx & 31;
        int gr = row0 + r;
        float4 v = {0.f, 0.f, 0.f, 0.f};
        if (gr < N) v = *(const float4*)(h + (size_t)gr * NCH + f4 * 4);
        half4 p = {(_Float16)v.x, (_Float16)v.y, (_Float16)v.z, (_Float16)v.w};
        *(half4*)&Xs[r][f4 * 4] = p;
    }
    *(uint4*)&Ws[tid >> 2][(tid & 3) * 8]        = pv0;
    *(uint4*)&Ws[64 + (tid >> 2)][(tid & 3) * 8] = pv1;
    __syncthreads();

    f32x4 acc[4][2];
    #pragma unroll
    for (int mb = 0; mb < 4; ++mb)
        #pragma unroll
        for (int nf = 0; nf < 2; ++nf) acc[mb][nf] = (f32x4){0.f, 0.f, 0.f, 0.f};

    for (int i = 0; i < 8; ++i) {
        if (i < 7) {
            int j = i + 1;
            const _Float16* nw = (j < 4) ? (w2c + j * 4096) : (w3c + (j - 4) * 4096);
            const uint4* s = (const uint4*)nw;
            pv0 = s[tid]; pv1 = s[tid + 256];
        }
        const int lc = i & 3;
        half8 av[4], bv[2];
        #pragma unroll
        for (int mb = 0; mb < 4; ++mb)
            av[mb] = *(const half8*)&Xs[mb * 16 + lrow][lc * 32 + lk8 * 8];
        #pragma unroll
        for (int nf = 0; nf < 2; ++nf)
            bv[nf] = *(const half8*)&Ws[n0 + nf * 16 + lrow][lk8 * 8];
        #pragma unroll
        for (int mb = 0; mb < 4; ++mb)
            #pragma unroll
            for (int nf = 0; nf < 2; ++nf)
                acc[mb][nf] = __builtin_amdgcn_mfma_f32_16x16x32_f16(
                    av[mb], bv[nf], acc[mb][nf], 0, 0, 0);

        __syncthreads();
        if (i == 3) {
            float bi0 = b2[n0 + lrow], bi1 = b2[n0 + 16 + lrow];
            #pragma unroll
            for (int mb = 0; mb < 4; ++mb)
                #pragma unroll
                for (int nf = 0; nf < 2; ++nf) {
                    float bb = nf ? bi1 : bi0;
                    #pragma unroll
                    for (int q = 0; q < 4; ++q) {
                        float g = fmaxf(acc[mb][nf][q] + bb, 0.f);
                        Xs[mb * 16 + lk8 * 4 + q][n0 + nf * 16 + lrow] = (_Float16)g;
                    }
                    acc[mb][nf] = (f32x4){0.f, 0.f, 0.f, 0.f};
                }
        }
        if (i < 7) {
            *(uint4*)&Ws[tid >> 2][(tid & 3) * 8]        = pv0;
            *(uint4*)&Ws[64 + (tid >> 2)][(tid & 3) * 8] = pv1;
        }
        __syncthreads();
    }

    float bi0 = b3[n0 + lrow], bi1 = b3[n0 + 16 + lrow];
    #pragma unroll
    for (int mb = 0; mb < 4; ++mb)
        #pragma unroll
        for (int q = 0; q < 4; ++q) {
            int gr = row0 + mb * 16 + lk8 * 4 + q;
            if (gr < N) {
                out[(size_t)gr * NCH + n0 + lrow]      = acc[mb][0][q] + bi0;
                out[(size_t)gr * NCH + n0 + 16 + lrow] = acc[mb][1][q] + bi1;
            }
        }
}

// ==================== fp32 fallback path (round-1, proven) ====================
__global__ __launch_bounds__(256) void k_atomwise1(
    const float* __restrict__ x, const float* __restrict__ w1,
    const float* __restrict__ b1, float* __restrict__ h,
    float* __restrict__ h2, int N)
{
    __shared__ float xs[16][NCH];
    const int row0 = blockIdx.x * 16;
    const int tid = threadIdx.x;
    #pragma unroll
    for (int t = 0; t < 8; ++t) {
        int idx = tid + t * 256;
        int r = idx >> 7, c = idx & 127;
        int gr = row0 + r;
        xs[r][c] = (gr < N) ? x[(size_t)gr * NCH + c] : 0.f;
    }
    __syncthreads();
    const int j = tid & 127;
    const int rg = tid >> 7;
    float acc[8];
    #pragma unroll
    for (int i = 0; i < 8; ++i) acc[i] = 0.f;
    for (int k = 0; k < NCH; ++k) {
        float wv = w1[(size_t)k * NCH + j];
        #pragma unroll
        for (int i = 0; i < 8; ++i)
            acc[i] = fmaf(xs[rg * 8 + i][k], wv, acc[i]);
    }
    float bv = b1[j];
    #pragma unroll
    for (int i = 0; i < 8; ++i) {
        int gr = row0 + rg * 8 + i;
        if (gr < N) {
            float v = acc[i] + bv;
            h[(size_t)gr * NCH + j]  = v;
            h2[(size_t)gr * NCH + j] = v;
        }
    }
}

__global__ __launch_bounds__(256) void k_edges_f32(
    const int* __restrict__ ei, const float* __restrict__ eattr,
    const float* __restrict__ xpos, const float* __restrict__ h,
    const float* __restrict__ mw1, const float* __restrict__ mb1,
    const float* __restrict__ mw2, const float* __restrict__ mb2,
    const float* __restrict__ mw3, const float* __restrict__ mb3,
    float* __restrict__ agg, int E)
{
    __shared__ __align__(16) float Asf[TE][292];
    __shared__ float Wsf[32][NCH];
    __shared__ int srcS[TE];
    __shared__ int dstS[TE];
    const int tid = threadIdx.x;
    const int e0 = blockIdx.x * TE;
    if (tid < TE) {
        int e = e0 + tid;
        int s = 0, d = -1;
        float r = 0.f;
        if (e < E) {
            s = ei[e]; d = ei[E + e];
            float dx = xpos[d * 3 + 0] - xpos[s * 3 + 0];
            float dy = xpos[d * 3 + 1] - xpos[s * 3 + 1];
            float dz = xpos[d * 3 + 2] - xpos[s * 3 + 2];
            r = sqrtf(dx * dx + dy * dy + dz * dz);
        }
        srcS[tid] = s; dstS[tid] = d;
        #pragma unroll
        for (int i = 0; i < 16; ++i) {
            float om = 10.f * exp2f(7.0f - 0.875f * (float)i);
            float f = r * om;
            Asf[tid][i] = sinf(f); Asf[tid][16 + i] = cosf(f);
        }
    }
    __syncthreads();
    {
        const int half = tid >> 7;
        const int c = tid & 127;
        for (int ee = 0; ee < TE; ee += 2) {
            int le = ee + half;
            int e = e0 + le;
            if (e < E) {
                Asf[le][32 + c]  = eattr[(size_t)e * NCH + c];
                Asf[le][160 + c] = h[(size_t)srcS[le] * NCH + c];
            } else { Asf[le][32 + c] = 0.f; Asf[le][160 + c] = 0.f; }
        }
    }
    const int jl = tid & 31;
    const int g  = tid >> 5;
    float acc[8][4];
    auto run_layer = [&](const float* __restrict__ Wg, int K) {
        #pragma unroll
        for (int i = 0; i < 8; ++i)
            #pragma unroll
            for (int c = 0; c < 4; ++c) acc[i][c] = 0.f;
        for (int k0 = 0; k0 < K; k0 += 32) {
            __syncthreads();
            #pragma unroll
            for (int t = 0; t < 16; ++t) {
                int idx = tid + t * 256;
                Wsf[idx >> 7][idx & 127] =
                    Wg[(size_t)(k0 + (idx >> 7)) * NCH + (idx & 127)];
            }
            __syncthreads();
            #pragma unroll
            for (int kk = 0; kk < 32; kk += 4) {
                float4 a[8];
                #pragma unroll
                for (int i = 0; i < 8; ++i)
                    a[i] = *reinterpret_cast<const float4*>(&Asf[g * 8 + i][k0 + kk]);
                #pragma unroll
                for (int u = 0; u < 4; ++u) {
                    float w0 = Wsf[kk + u][jl];
                    float w1v = Wsf[kk + u][jl + 32];
                    float w2v = Wsf[kk + u][jl + 64];
                    float w3v = Wsf[kk + u][jl + 96];
                    #pragma unroll
                    for (int i = 0; i < 8; ++i) {
                        float avv = (&a[i].x)[u];
                        acc[i][0] = fmaf(avv, w0, acc[i][0]);
                        acc[i][1] = fmaf(avv, w1v, acc[i][1]);
                        acc[i][2] = fmaf(avv, w2v, acc[i][2]);
                        acc[i][3] = fmaf(avv, w3v, acc[i][3]);
                    }
                }
            }
        }
    };
    run_layer(mw1, 288);
    #pragma unroll
    for (int i = 0; i < 8; ++i)
        #pragma unroll
        for (int c = 0; c < 4; ++c) {
            int j = jl + 32 * c;
            Asf[g * 8 + i][j] = gelu_exact(acc[i][c] + mb1[j]);
        }
    run_layer(mw2, 128);
    #pragma unroll
    for (int i = 0; i < 8; ++i)
        #pragma unroll
        for (int c = 0; c < 4; ++c) {
            int j = jl + 32 * c;
            Asf[g * 8 + i][j] = gelu_exact(acc[i][c] + mb2[j]);
        }
    run_layer(mw3, 128);
    #pragma unroll
    for (int i = 0; i < 8; ++i) {
        int d = dstS[g * 8 + i];
        if (d >= 0) {
            #pragma unroll
            for (int c = 0; c < 4; ++c) {
                int j = jl + 32 * c;
                atomicAdd(&agg[(size_t)d * NCH + j], acc[i][c] + mb3[j]);
            }
        }
    }
}

__global__ __launch_bounds__(256) void k_out(
    const float* h, const float* aggOpt,
    const float* __restrict__ w2, const float* __restrict__ b2,
    const float* __restrict__ w3, const float* __restrict__ b3,
    float* out, int N)
{
    __shared__ float hs[16][NCH];
    __shared__ float ts[16][NCH];
    const int row0 = blockIdx.x * 16;
    const int tid = threadIdx.x;
    #pragma unroll
    for (int t = 0; t < 8; ++t) {
        int idx = tid + t * 256;
        int r = idx >> 7, c = idx & 127;
        int gr = row0 + r;
        float v = 0.f;
        if (gr < N) {
            v = h[(size_t)gr * NCH + c];
            if (aggOpt) v += aggOpt[(size_t)gr * NCH + c];
        }
        hs[r][c] = v;
    }
    __syncthreads();
    const int j = tid & 127;
    const int rg = tid >> 7;
    float acc[8];
    #pragma unroll
    for (int i = 0; i < 8; ++i) acc[i] = 0.f;
    for (int k = 0; k < NCH; ++k) {
        float wv = w2[(size_t)k * NCH + j];
        #pragma unroll
        for (int i = 0; i < 8; ++i)
            acc[i] = fmaf(hs[rg * 8 + i][k], wv, acc[i]);
    }
    float bv = b2[j];
    #pragma unroll
    for (int i = 0; i < 8; ++i)
        ts[rg * 8 + i][j] = fmaxf(acc[i] + bv, 0.f);
    __syncthreads();
    float acc2[8];
    #pragma unroll
    for (int i = 0; i < 8; ++i) acc2[i] = 0.f;
    for (int k = 0; k < NCH; ++k) {
        float wv = w3[(size_t)k * NCH + j];
        #pragma unroll
        for (int i = 0; i < 8; ++i)
            acc2[i] = fmaf(ts[rg * 8 + i][k], wv, acc2[i]);
    }
    float b3v = b3[j];
    #pragma unroll
    for (int i = 0; i < 8; ++i) {
        int gr = row0 + rg * 8 + i;
        if (gr < N) out[(size_t)gr * NCH + j] = acc2[i] + b3v;
    }
}

extern "C" void kernel_launch(void* const* d_in, const int* in_sizes, int n_in,
                              void* d_out, int out_size, void* d_ws, size_t ws_size,
                              hipStream_t stream)
{
    const float* x     = (const float*)d_in[0];
    const int*   ei    = (const int*)d_in[1];
    const float* eattr = (const float*)d_in[2];
    const float* xpos  = (const float*)d_in[3];
    const float* w1    = (const float*)d_in[4];
    const float* b1    = (const float*)d_in[5];
    const float* mw1   = (const float*)d_in[6];
    const float* mb1   = (const float*)d_in[7];
    const float* mw2   = (const float*)d_in[8];
    const float* mb2   = (const float*)d_in[9];
    const float* mw3   = (const float*)d_in[10];
    const float* mb3   = (const float*)d_in[11];
    const float* w2    = (const float*)d_in[12];
    const float* b2    = (const float*)d_in[13];
    const float* w3    = (const float*)d_in[14];
    const float* b3    = (const float*)d_in[15];

    const int N = in_sizes[0] / NCH;
    const int E = in_sizes[1] / 2;

    float* h = (float*)d_out;

    const size_t h2_bytes = (size_t)N * NCH * sizeof(_Float16);
    const size_t wchunks  = 17 + 4 + 4 + 4;   // wf(mw1|mw2|mw3) + aw1 + o2 + o3
    const size_t wbytes   = wchunks * 4096 * sizeof(_Float16);
    const bool fast = ws_size >= h2_bytes + wbytes;

    if (fast) {
        _Float16* h2   = (_Float16*)d_ws;
        _Float16* wf   = (_Float16*)((char*)d_ws + h2_bytes);  // 17 chunks, frag order
        _Float16* aw1c = wf + 17 * 4096;
        _Float16* o2c  = aw1c + 4 * 4096;
        _Float16* o3c  = o2c + 4 * 4096;
        k_prep_frag<<<18, 256, 0, stream>>>(mw1, wf, 9);
        k_prep_frag<<<8, 256, 0, stream>>>(mw2, wf + 9 * 4096, 4);
        k_prep_frag<<<8, 256, 0, stream>>>(mw3, wf + 13 * 4096, 4);
        k_prep<<<64, 256, 0, stream>>>(w1, aw1c, 128 * 128);
        k_prep<<<64, 256, 0, stream>>>(w2, o2c, 128 * 128);
        k_prep<<<64, 256, 0, stream>>>(w3, o3c, 128 * 128);
        const int nb = (N + 63) / 64;
        k_aw1_mfma<<<nb, 256, 0, stream>>>(x, aw1c, b1, h, h2, N);
        k_edges_mfma<<<(E + TE - 1) / TE, 256, 0, stream>>>(
            ei, eattr, xpos, h2, h, wf, mb1, mb2, mb3, E);
        k_out_mfma<<<nb, 256, 0, stream>>>(h, o2c, b2, o3c, b3, (float*)d_out, N);
    } else {
        float* agg = (float*)d_ws;
        k_atomwise1<<<(N + 15) / 16, 256, 0, stream>>>(x, w1, b1, h, agg, N);
        hipMemsetAsync(agg, 0, (size_t)N * NCH * sizeof(float), stream);
        k_edges_f32<<<(E + TE - 1) / TE, 256, 0, stream>>>(
            ei, eattr, xpos, h, mw1, mb1, mw2, mb2, mw3, mb3, agg, E);
        k_out<<<(N + 15) / 16, 256, 0, stream>>>(h, agg, w2, b2, w3, b3,
                                                 (float*)d_out, N);
    }
}

// Round 5
// 463.653 us; speedup vs baseline: 10.7315x; 1.1806x over previous
//
#include <hip/hip_runtime.h>
#include <math.h>

#define NCH 128
#define TE 64    // fallback edge tile
#define TF 32    // fast-path edge tile (19 KB LDS -> 8 blocks/CU)
#define AP 296   // msg_in row pad (f16): stride 148 words, uniform 8 words/bank on b128
#define WP 40    // (LDS-staged weight kernels only)
#define XP 136   // node-tile row pad (f16)

typedef __attribute__((ext_vector_type(8))) _Float16 half8;
typedef __attribute__((ext_vector_type(4))) _Float16 half4;
typedef __attribute__((ext_vector_type(4))) float f32x4;

__device__ __forceinline__ float gelu_exact(float v) {
    return 0.5f * v * (1.0f + erff(v * 0.70710678118654752f));
}

// sin/cos of (rev * 2*pi) via HW v_sin/v_cos (input in revolutions, fract-reduced)
__device__ __forceinline__ void sincos_rev(float rev, float* s, float* c) {
    float fr = rev - floorf(rev);
#if __has_builtin(__builtin_amdgcn_sinf) && __has_builtin(__builtin_amdgcn_cosf)
    *s = __builtin_amdgcn_sinf(fr);
    *c = __builtin_amdgcn_cosf(fr);
#else
    float rad = fr * 6.283185307179586f;
    *s = sinf(rad);
    *c = cosf(rad);
#endif
}

// ============ prep A: W[K][128] fp32 -> k-chunked transposed f16 [K/32][128][32]
__global__ __launch_bounds__(256) void k_prep(const float* __restrict__ W,
                                              _Float16* __restrict__ out, int total) {
    int idx = blockIdx.x * 256 + threadIdx.x;
    if (idx >= total) return;
    int k = idx >> 7, n = idx & 127;
    out[(size_t)(k >> 5) * 4096 + n * 32 + (k & 31)] = (_Float16)W[idx];
}

// ============ prep B: W[K][128] fp32 -> per-lane MFMA fragment order
// layout: [chunk][wave(4)][nf(2)][lane(64)][8 f16]
__global__ __launch_bounds__(256) void k_prep_frag(const float* __restrict__ W,
                                                   _Float16* __restrict__ out,
                                                   int nchunks) {
    int idx = blockIdx.x * 256 + threadIdx.x;
    if (idx >= nchunks * 512) return;
    int c    = idx >> 9;
    int r    = idx & 511;
    int wv   = r >> 7;
    int nf   = (r >> 6) & 1;
    int lane = r & 63;
    int n  = wv * 32 + nf * 16 + (lane & 15);
    int k0 = c * 32 + (lane >> 4) * 8;
    half8 v;
    #pragma unroll
    for (int j = 0; j < 8; ++j) v[j] = (_Float16)W[(size_t)(k0 + j) * NCH + n];
    *(half8*)(out + (size_t)idx * 8) = v;
}

// ============ Kernel 1 (fast): h = x@w1+b1 via MFMA -> h fp32 (d_out) + h2 f16
__global__ __launch_bounds__(256, 4) void k_aw1_mfma(
    const float* __restrict__ x, const _Float16* __restrict__ wc,
    const float* __restrict__ b1, float* __restrict__ h,
    _Float16* __restrict__ h2, int N)
{
    __shared__ __align__(16) _Float16 Xs[64][XP];
    __shared__ __align__(16) _Float16 Ws[128][WP];

    const int tid  = threadIdx.x;
    const int row0 = blockIdx.x * 64;
    const int lane = tid & 63;
    const int w    = tid >> 6;
    const int lrow = lane & 15;
    const int lk8  = lane >> 4;
    const int n0   = w * 32;

    const uint4* wsrc = (const uint4*)wc;
    uint4 pv0 = wsrc[tid], pv1 = wsrc[tid + 256];

    #pragma unroll
    for (int t = 0; t < 8; ++t) {
        int idx = tid + t * 256;
        int r = idx >> 5, f4 = idx & 31;
        int gr = row0 + r;
        float4 v = {0.f, 0.f, 0.f, 0.f};
        if (gr < N) v = *(const float4*)(x + (size_t)gr * NCH + f4 * 4);
        half4 p = {(_Float16)v.x, (_Float16)v.y, (_Float16)v.z, (_Float16)v.w};
        *(half4*)&Xs[r][f4 * 4] = p;
    }
    *(uint4*)&Ws[tid >> 2][(tid & 3) * 8]        = pv0;
    *(uint4*)&Ws[64 + (tid >> 2)][(tid & 3) * 8] = pv1;
    __syncthreads();

    f32x4 acc[4][2];
    #pragma unroll
    for (int mb = 0; mb < 4; ++mb)
        #pragma unroll
        for (int nf = 0; nf < 2; ++nf) acc[mb][nf] = (f32x4){0.f, 0.f, 0.f, 0.f};

    for (int i = 0; i < 4; ++i) {
        if (i < 3) {
            const uint4* s = (const uint4*)(wc + (i + 1) * 4096);
            pv0 = s[tid]; pv1 = s[tid + 256];
        }
        half8 av[4], bv[2];
        #pragma unroll
        for (int mb = 0; mb < 4; ++mb)
            av[mb] = *(const half8*)&Xs[mb * 16 + lrow][i * 32 + lk8 * 8];
        #pragma unroll
        for (int nf = 0; nf < 2; ++nf)
            bv[nf] = *(const half8*)&Ws[n0 + nf * 16 + lrow][lk8 * 8];
        #pragma unroll
        for (int mb = 0; mb < 4; ++mb)
            #pragma unroll
            for (int nf = 0; nf < 2; ++nf)
                acc[mb][nf] = __builtin_amdgcn_mfma_f32_16x16x32_f16(
                    av[mb], bv[nf], acc[mb][nf], 0, 0, 0);
        __syncthreads();
        if (i < 3) {
            *(uint4*)&Ws[tid >> 2][(tid & 3) * 8]        = pv0;
            *(uint4*)&Ws[64 + (tid >> 2)][(tid & 3) * 8] = pv1;
        }
        __syncthreads();
    }

    float bi0 = b1[n0 + lrow], bi1 = b1[n0 + 16 + lrow];
    #pragma unroll
    for (int mb = 0; mb < 4; ++mb)
        #pragma unroll
        for (int q = 0; q < 4; ++q) {
            int gr = row0 + mb * 16 + lk8 * 4 + q;
            if (gr < N) {
                float v0 = acc[mb][0][q] + bi0;
                float v1 = acc[mb][1][q] + bi1;
                h[(size_t)gr * NCH + n0 + lrow]       = v0;
                h[(size_t)gr * NCH + n0 + 16 + lrow]  = v1;
                h2[(size_t)gr * NCH + n0 + lrow]      = (_Float16)v0;
                h2[(size_t)gr * NCH + n0 + 16 + lrow] = (_Float16)v1;
            }
        }
}

// ============ Kernel 2 (fast): edge MLP — TF=32 tile, 8 blocks/CU, native trig
__global__ __launch_bounds__(256, 8) void k_edges_mfma(
    const int* __restrict__ ei, const float* __restrict__ eattr,
    const float* __restrict__ xpos, const _Float16* __restrict__ h2,
    float* h,   // atomic target (aliases d_out)
    const _Float16* __restrict__ wf,   // fragment-packed mw1|mw2|mw3 (17 chunks)
    const float* __restrict__ mb1, const float* __restrict__ mb2,
    const float* __restrict__ mb3, int E)
{
    __shared__ __align__(16) _Float16 As[TF][AP];   // 18944 B

    const int tid  = threadIdx.x;
    const int e0   = blockIdx.x * TF;
    const int lane = tid & 63;
    const int w    = tid >> 6;
    const int lrow = lane & 15;
    const int lk8  = lane >> 4;
    const int n0   = w * 32;

    // ---- T14 stage: issue ALL global loads first, compute trig under them
    float4 ea[4];
    #pragma unroll
    for (int t = 0; t < 4; ++t) {
        int idx = tid + t * 256;
        int e = e0 + (idx >> 5);
        ea[t] = (e < E) ? *(const float4*)(eattr + (size_t)e * NCH + (idx & 31) * 4)
                        : (float4){0.f, 0.f, 0.f, 0.f};
    }
    uint4 hv[2];
    #pragma unroll
    for (int t = 0; t < 2; ++t) {
        int idx = tid + t * 256;
        int e = e0 + (idx >> 4);
        int s = (e < E) ? ei[e] : 0;
        hv[t] = *(const uint4*)(h2 + (size_t)s * NCH + (idx & 15) * 8);
    }

    // trig: 8 threads per edge, 2 (sin,cos) pairs each — HW v_sin/v_cos
    {
        int le = tid >> 3, i0 = tid & 7;
        int ge = e0 + le;
        float r = 0.f;
        if (ge < E) {
            int s = ei[ge], d = ei[E + ge];
            float dx = xpos[d * 3 + 0] - xpos[s * 3 + 0];
            float dy = xpos[d * 3 + 1] - xpos[s * 3 + 1];
            float dz = xpos[d * 3 + 2] - xpos[s * 3 + 2];
            r = sqrtf(dx * dx + dy * dy + dz * dz);
        }
        #pragma unroll
        for (int u = 0; u < 2; ++u) {
            int i = i0 + u * 8;
            // omega_i/(2*pi) = 10*128^(1-i/8) * 0.15915494
            float omr = 1.5915494309f * exp2f(7.0f - 0.875f * (float)i);
            float sv, cv;
            sincos_rev(r * omr, &sv, &cv);
            As[le][i]      = (_Float16)sv;
            As[le][16 + i] = (_Float16)cv;
        }
    }
    // write-late: convert eattr, copy h2
    #pragma unroll
    for (int t = 0; t < 4; ++t) {
        int idx = tid + t * 256;
        half4 p = {(_Float16)ea[t].x, (_Float16)ea[t].y,
                   (_Float16)ea[t].z, (_Float16)ea[t].w};
        *(half4*)&As[idx >> 5][32 + (idx & 31) * 4] = p;
    }
    #pragma unroll
    for (int t = 0; t < 2; ++t) {
        int idx = tid + t * 256;
        *(uint4*)&As[idx >> 4][160 + (idx & 15) * 8] = hv[t];
    }
    __syncthreads();

    f32x4 acc[2][2];
    #pragma unroll
    for (int mb = 0; mb < 2; ++mb)
        #pragma unroll
        for (int nf = 0; nf < 2; ++nf) acc[mb][nf] = (f32x4){0.f, 0.f, 0.f, 0.f};

    // B fragment: wf in half8 units — chunk stride 512, wave 128, nf 64, lane 1
    const half8* bp = (const half8*)wf;
    const int bbase = w * 128 + lane;

    auto epi = [&](const float* __restrict__ mbv) {
        float bi0 = mbv[n0 + lrow], bi1 = mbv[n0 + 16 + lrow];
        #pragma unroll
        for (int mb = 0; mb < 2; ++mb)
            #pragma unroll
            for (int nf = 0; nf < 2; ++nf) {
                float bb = nf ? bi1 : bi0;
                #pragma unroll
                for (int q = 0; q < 4; ++q) {
                    float g = gelu_exact(acc[mb][nf][q] + bb);
                    As[mb * 16 + lk8 * 4 + q][n0 + nf * 16 + lrow] = (_Float16)g;
                }
                acc[mb][nf] = (f32x4){0.f, 0.f, 0.f, 0.f};
            }
    };

    // ---- layer 1: 9 chunks, barrier-free
    #pragma unroll
    for (int c = 0; c < 9; ++c) {
        half8 b0 = bp[(size_t)c * 512 + bbase];
        half8 b1 = bp[(size_t)c * 512 + bbase + 64];
        #pragma unroll
        for (int mb = 0; mb < 2; ++mb) {
            half8 av = *(const half8*)&As[mb * 16 + lrow][c * 32 + lk8 * 8];
            acc[mb][0] = __builtin_amdgcn_mfma_f32_16x16x32_f16(av, b0, acc[mb][0], 0, 0, 0);
            acc[mb][1] = __builtin_amdgcn_mfma_f32_16x16x32_f16(av, b1, acc[mb][1], 0, 0, 0);
        }
    }
    __syncthreads();        // all layer-1 A-reads done
    epi(mb1);
    __syncthreads();        // gelu writes visible

    // ---- layer 2: 4 chunks
    #pragma unroll
    for (int c = 0; c < 4; ++c) {
        half8 b0 = bp[(size_t)(9 + c) * 512 + bbase];
        half8 b1 = bp[(size_t)(9 + c) * 512 + bbase + 64];
        #pragma unroll
        for (int mb = 0; mb < 2; ++mb) {
            half8 av = *(const half8*)&As[mb * 16 + lrow][c * 32 + lk8 * 8];
            acc[mb][0] = __builtin_amdgcn_mfma_f32_16x16x32_f16(av, b0, acc[mb][0], 0, 0, 0);
            acc[mb][1] = __builtin_amdgcn_mfma_f32_16x16x32_f16(av, b1, acc[mb][1], 0, 0, 0);
        }
    }
    __syncthreads();
    epi(mb2);
    __syncthreads();

    // ---- layer 3: 4 chunks
    #pragma unroll
    for (int c = 0; c < 4; ++c) {
        half8 b0 = bp[(size_t)(13 + c) * 512 + bbase];
        half8 b1 = bp[(size_t)(13 + c) * 512 + bbase + 64];
        #pragma unroll
        for (int mb = 0; mb < 2; ++mb) {
            half8 av = *(const half8*)&As[mb * 16 + lrow][c * 32 + lk8 * 8];
            acc[mb][0] = __builtin_amdgcn_mfma_f32_16x16x32_f16(av, b0, acc[mb][0], 0, 0, 0);
            acc[mb][1] = __builtin_amdgcn_mfma_f32_16x16x32_f16(av, b1, acc[mb][1], 0, 0, 0);
        }
    }

    // ---- bias + scatter-add into h
    {
        float bi0 = mb3[n0 + lrow], bi1 = mb3[n0 + 16 + lrow];
        #pragma unroll
        for (int mb = 0; mb < 2; ++mb)
            #pragma unroll
            for (int q = 0; q < 4; ++q) {
                int e = e0 + mb * 16 + lk8 * 4 + q;
                if (e < E) {
                    int d = ei[E + e];
                    atomicAdd(h + (size_t)d * NCH + n0 + lrow,      acc[mb][0][q] + bi0);
                    atomicAdd(h + (size_t)d * NCH + n0 + 16 + lrow, acc[mb][1][q] + bi1);
                }
            }
    }
}

// ============ Kernel 3 (fast): out = relu(h@w2+b2)@w3+b3 via MFMA, in-place
__global__ __launch_bounds__(256, 4) void k_out_mfma(
    const float* h, const _Float16* __restrict__ w2c,
    const float* __restrict__ b2, const _Float16* __restrict__ w3c,
    const float* __restrict__ b3, float* out, int N)
{
    __shared__ __align__(16) _Float16 Xs[64][XP];
    __shared__ __align__(16) _Float16 Ws[128][WP];

    const int tid  = threadIdx.x;
    const int row0 = blockIdx.x * 64;
    const int lane = tid & 63;
    const int w    = tid >> 6;
    const int lrow = lane & 15;
    const int lk8  = lane >> 4;
    const int n0   = w * 32;

    const uint4* wsrc = (const uint4*)w2c;
    uint4 pv0 = wsrc[tid], pv1 = wsrc[tid + 256];

    #pragma unroll
    for (int t = 0; t < 8; ++t) {
        int idx = tid + t * 256;
        int r = idx >> 5, f4 = idx & 31;
        int gr = row0 + r;
        float4 v = {0.f, 0.f, 0.f, 0.f};
        if (gr < N) v = *(const float4*)(h + (size_t)gr * NCH + f4 * 4);
        half4 p = {(_Float16)v.x, (_Float16)v.y, (_Float16)v.z, (_Float16)v.w};
        *(half4*)&Xs[r][f4 * 4] = p;
    }
    *(uint4*)&Ws[tid >> 2][(tid & 3) * 8]        = pv0;
    *(uint4*)&Ws[64 + (tid >> 2)][(tid & 3) * 8] = pv1;
    __syncthreads();

    f32x4 acc[4][2];
    #pragma unroll
    for (int mb = 0; mb < 4; ++mb)
        #pragma unroll
        for (int nf = 0; nf < 2; ++nf) acc[mb][nf] = (f32x4){0.f, 0.f, 0.f, 0.f};

    for (int i = 0; i < 8; ++i) {
        if (i < 7) {
            int j = i + 1;
            const _Float16* nw = (j < 4) ? (w2c + j * 4096) : (w3c + (j - 4) * 4096);
            const uint4* s = (const uint4*)nw;
            pv0 = s[tid]; pv1 = s[tid + 256];
        }
        const int lc = i & 3;
        half8 av[4], bv[2];
        #pragma unroll
        for (int mb = 0; mb < 4; ++mb)
            av[mb] = *(const half8*)&Xs[mb * 16 + lrow][lc * 32 + lk8 * 8];
        #pragma unroll
        for (int nf = 0; nf < 2; ++nf)
            bv[nf] = *(const half8*)&Ws[n0 + nf * 16 + lrow][lk8 * 8];
        #pragma unroll
        for (int mb = 0; mb < 4; ++mb)
            #pragma unroll
            for (int nf = 0; nf < 2; ++nf)
                acc[mb][nf] = __builtin_amdgcn_mfma_f32_16x16x32_f16(
                    av[mb], bv[nf], acc[mb][nf], 0, 0, 0);

        __syncthreads();
        if (i == 3) {
            float bi0 = b2[n0 + lrow], bi1 = b2[n0 + 16 + lrow];
            #pragma unroll
            for (int mb = 0; mb < 4; ++mb)
                #pragma unroll
                for (int nf = 0; nf < 2; ++nf) {
                    float bb = nf ? bi1 : bi0;
                    #pragma unroll
                    for (int q = 0; q < 4; ++q) {
                        float g = fmaxf(acc[mb][nf][q] + bb, 0.f);
                        Xs[mb * 16 + lk8 * 4 + q][n0 + nf * 16 + lrow] = (_Float16)g;
                    }
                    acc[mb][nf] = (f32x4){0.f, 0.f, 0.f, 0.f};
                }
        }
        if (i < 7) {
            *(uint4*)&Ws[tid >> 2][(tid & 3) * 8]        = pv0;
            *(uint4*)&Ws[64 + (tid >> 2)][(tid & 3) * 8] = pv1;
        }
        __syncthreads();
    }

    float bi0 = b3[n0 + lrow], bi1 = b3[n0 + 16 + lrow];
    #pragma unroll
    for (int mb = 0; mb < 4; ++mb)
        #pragma unroll
        for (int q = 0; q < 4; ++q) {
            int gr = row0 + mb * 16 + lk8 * 4 + q;
            if (gr < N) {
                out[(size_t)gr * NCH + n0 + lrow]      = acc[mb][0][q] + bi0;
                out[(size_t)gr * NCH + n0 + 16 + lrow] = acc[mb][1][q] + bi1;
            }
        }
}

// ==================== fp32 fallback path (round-1, proven) ====================
__global__ __launch_bounds__(256) void k_atomwise1(
    const float* __restrict__ x, const float* __restrict__ w1,
    const float* __restrict__ b1, float* __restrict__ h,
    float* __restrict__ h2, int N)
{
    __shared__ float xs[16][NCH];
    const int row0 = blockIdx.x * 16;
    const int tid = threadIdx.x;
    #pragma unroll
    for (int t = 0; t < 8; ++t) {
        int idx = tid + t * 256;
        int r = idx >> 7, c = idx & 127;
        int gr = row0 + r;
        xs[r][c] = (gr < N) ? x[(size_t)gr * NCH + c] : 0.f;
    }
    __syncthreads();
    const int j = tid & 127;
    const int rg = tid >> 7;
    float acc[8];
    #pragma unroll
    for (int i = 0; i < 8; ++i) acc[i] = 0.f;
    for (int k = 0; k < NCH; ++k) {
        float wv = w1[(size_t)k * NCH + j];
        #pragma unroll
        for (int i = 0; i < 8; ++i)
            acc[i] = fmaf(xs[rg * 8 + i][k], wv, acc[i]);
    }
    float bv = b1[j];
    #pragma unroll
    for (int i = 0; i < 8; ++i) {
        int gr = row0 + rg * 8 + i;
        if (gr < N) {
            float v = acc[i] + bv;
            h[(size_t)gr * NCH + j]  = v;
            h2[(size_t)gr * NCH + j] = v;
        }
    }
}

__global__ __launch_bounds__(256) void k_edges_f32(
    const int* __restrict__ ei, const float* __restrict__ eattr,
    const float* __restrict__ xpos, const float* __restrict__ h,
    const float* __restrict__ mw1, const float* __restrict__ mb1,
    const float* __restrict__ mw2, const float* __restrict__ mb2,
    const float* __restrict__ mw3, const float* __restrict__ mb3,
    float* __restrict__ agg, int E)
{
    __shared__ __align__(16) float Asf[TE][292];
    __shared__ float Wsf[32][NCH];
    __shared__ int srcS[TE];
    __shared__ int dstS[TE];
    const int tid = threadIdx.x;
    const int e0 = blockIdx.x * TE;
    if (tid < TE) {
        int e = e0 + tid;
        int s = 0, d = -1;
        float r = 0.f;
        if (e < E) {
            s = ei[e]; d = ei[E + e];
            float dx = xpos[d * 3 + 0] - xpos[s * 3 + 0];
            float dy = xpos[d * 3 + 1] - xpos[s * 3 + 1];
            float dz = xpos[d * 3 + 2] - xpos[s * 3 + 2];
            r = sqrtf(dx * dx + dy * dy + dz * dz);
        }
        srcS[tid] = s; dstS[tid] = d;
        #pragma unroll
        for (int i = 0; i < 16; ++i) {
            float om = 10.f * exp2f(7.0f - 0.875f * (float)i);
            float f = r * om;
            Asf[tid][i] = sinf(f); Asf[tid][16 + i] = cosf(f);
        }
    }
    __syncthreads();
    {
        const int half = tid >> 7;
        const int c = tid & 127;
        for (int ee = 0; ee < TE; ee += 2) {
            int le = ee + half;
            int e = e0 + le;
            if (e < E) {
                Asf[le][32 + c]  = eattr[(size_t)e * NCH + c];
                Asf[le][160 + c] = h[(size_t)srcS[le] * NCH + c];
            } else { Asf[le][32 + c] = 0.f; Asf[le][160 + c] = 0.f; }
        }
    }
    const int jl = tid & 31;
    const int g  = tid >> 5;
    float acc[8][4];
    auto run_layer = [&](const float* __restrict__ Wg, int K) {
        #pragma unroll
        for (int i = 0; i < 8; ++i)
            #pragma unroll
            for (int c = 0; c < 4; ++c) acc[i][c] = 0.f;
        for (int k0 = 0; k0 < K; k0 += 32) {
            __syncthreads();
            #pragma unroll
            for (int t = 0; t < 16; ++t) {
                int idx = tid + t * 256;
                Wsf[idx >> 7][idx & 127] =
                    Wg[(size_t)(k0 + (idx >> 7)) * NCH + (idx & 127)];
            }
            __syncthreads();
            #pragma unroll
            for (int kk = 0; kk < 32; kk += 4) {
                float4 a[8];
                #pragma unroll
                for (int i = 0; i < 8; ++i)
                    a[i] = *reinterpret_cast<const float4*>(&Asf[g * 8 + i][k0 + kk]);
                #pragma unroll
                for (int u = 0; u < 4; ++u) {
                    float w0 = Wsf[kk + u][jl];
                    float w1v = Wsf[kk + u][jl + 32];
                    float w2v = Wsf[kk + u][jl + 64];
                    float w3v = Wsf[kk + u][jl + 96];
                    #pragma unroll
                    for (int i = 0; i < 8; ++i) {
                        float avv = (&a[i].x)[u];
                        acc[i][0] = fmaf(avv, w0, acc[i][0]);
                        acc[i][1] = fmaf(avv, w1v, acc[i][1]);
                        acc[i][2] = fmaf(avv, w2v, acc[i][2]);
                        acc[i][3] = fmaf(avv, w3v, acc[i][3]);
                    }
                }
            }
        }
    };
    run_layer(mw1, 288);
    #pragma unroll
    for (int i = 0; i < 8; ++i)
        #pragma unroll
        for (int c = 0; c < 4; ++c) {
            int j = jl + 32 * c;
            Asf[g * 8 + i][j] = gelu_exact(acc[i][c] + mb1[j]);
        }
    run_layer(mw2, 128);
    #pragma unroll
    for (int i = 0; i < 8; ++i)
        #pragma unroll
        for (int c = 0; c < 4; ++c) {
            int j = jl + 32 * c;
            Asf[g * 8 + i][j] = gelu_exact(acc[i][c] + mb2[j]);
        }
    run_layer(mw3, 128);
    #pragma unroll
    for (int i = 0; i < 8; ++i) {
        int d = dstS[g * 8 + i];
        if (d >= 0) {
            #pragma unroll
            for (int c = 0; c < 4; ++c) {
                int j = jl + 32 * c;
                atomicAdd(&agg[(size_t)d * NCH + j], acc[i][c] + mb3[j]);
            }
        }
    }
}

__global__ __launch_bounds__(256) void k_out(
    const float* h, const float* aggOpt,
    const float* __restrict__ w2, const float* __restrict__ b2,
    const float* __restrict__ w3, const float* __restrict__ b3,
    float* out, int N)
{
    __shared__ float hs[16][NCH];
    __shared__ float ts[16][NCH];
    const int row0 = blockIdx.x * 16;
    const int tid = threadIdx.x;
    #pragma unroll
    for (int t = 0; t < 8; ++t) {
        int idx = tid + t * 256;
        int r = idx >> 7, c = idx & 127;
        int gr = row0 + r;
        float v = 0.f;
        if (gr < N) {
            v = h[(size_t)gr * NCH + c];
            if (aggOpt) v += aggOpt[(size_t)gr * NCH + c];
        }
        hs[r][c] = v;
    }
    __syncthreads();
    const int j = tid & 127;
    const int rg = tid >> 7;
    float acc[8];
    #pragma unroll
    for (int i = 0; i < 8; ++i) acc[i] = 0.f;
    for (int k = 0; k < NCH; ++k) {
        float wv = w2[(size_t)k * NCH + j];
        #pragma unroll
        for (int i = 0; i < 8; ++i)
            acc[i] = fmaf(hs[rg * 8 + i][k], wv, acc[i]);
    }
    float bv = b2[j];
    #pragma unroll
    for (int i = 0; i < 8; ++i)
        ts[rg * 8 + i][j] = fmaxf(acc[i] + bv, 0.f);
    __syncthreads();
    float acc2[8];
    #pragma unroll
    for (int i = 0; i < 8; ++i) acc2[i] = 0.f;
    for (int k = 0; k < NCH; ++k) {
        float wv = w3[(size_t)k * NCH + j];
        #pragma unroll
        for (int i = 0; i < 8; ++i)
            acc2[i] = fmaf(ts[rg * 8 + i][k], wv, acc2[i]);
    }
    float b3v = b3[j];
    #pragma unroll
    for (int i = 0; i < 8; ++i) {
        int gr = row0 + rg * 8 + i;
        if (gr < N) out[(size_t)gr * NCH + j] = acc2[i] + b3v;
    }
}

extern "C" void kernel_launch(void* const* d_in, const int* in_sizes, int n_in,
                              void* d_out, int out_size, void* d_ws, size_t ws_size,
                              hipStream_t stream)
{
    const float* x     = (const float*)d_in[0];
    const int*   ei    = (const int*)d_in[1];
    const float* eattr = (const float*)d_in[2];
    const float* xpos  = (const float*)d_in[3];
    const float* w1    = (const float*)d_in[4];
    const float* b1    = (const float*)d_in[5];
    const float* mw1   = (const float*)d_in[6];
    const float* mb1   = (const float*)d_in[7];
    const float* mw2   = (const float*)d_in[8];
    const float* mb2   = (const float*)d_in[9];
    const float* mw3   = (const float*)d_in[10];
    const float* mb3   = (const float*)d_in[11];
    const float* w2    = (const float*)d_in[12];
    const float* b2    = (const float*)d_in[13];
    const float* w3    = (const float*)d_in[14];
    const float* b3    = (const float*)d_in[15];

    const int N = in_sizes[0] / NCH;
    const int E = in_sizes[1] / 2;

    float* h = (float*)d_out;

    const size_t h2_bytes = (size_t)N * NCH * sizeof(_Float16);
    const size_t wchunks  = 17 + 4 + 4 + 4;   // wf(mw1|mw2|mw3) + aw1 + o2 + o3
    const size_t wbytes   = wchunks * 4096 * sizeof(_Float16);
    const bool fast = ws_size >= h2_bytes + wbytes;

    if (fast) {
        _Float16* h2   = (_Float16*)d_ws;
        _Float16* wf   = (_Float16*)((char*)d_ws + h2_bytes);  // 17 chunks, frag order
        _Float16* aw1c = wf + 17 * 4096;
        _Float16* o2c  = aw1c + 4 * 4096;
        _Float16* o3c  = o2c + 4 * 4096;
        k_prep_frag<<<18, 256, 0, stream>>>(mw1, wf, 9);
        k_prep_frag<<<8, 256, 0, stream>>>(mw2, wf + 9 * 4096, 4);
        k_prep_frag<<<8, 256, 0, stream>>>(mw3, wf + 13 * 4096, 4);
        k_prep<<<64, 256, 0, stream>>>(w1, aw1c, 128 * 128);
        k_prep<<<64, 256, 0, stream>>>(w2, o2c, 128 * 128);
        k_prep<<<64, 256, 0, stream>>>(w3, o3c, 128 * 128);
        const int nb = (N + 63) / 64;
        k_aw1_mfma<<<nb, 256, 0, stream>>>(x, aw1c, b1, h, h2, N);
        k_edges_mfma<<<(E + TF - 1) / TF, 256, 0, stream>>>(
            ei, eattr, xpos, h2, h, wf, mb1, mb2, mb3, E);
        k_out_mfma<<<nb, 256, 0, stream>>>(h, o2c, b2, o3c, b3, (float*)d_out, N);
    } else {
        float* agg = (float*)d_ws;
        k_atomwise1<<<(N + 15) / 16, 256, 0, stream>>>(x, w1, b1, h, agg, N);
        hipMemsetAsync(agg, 0, (size_t)N * NCH * sizeof(float), stream);
        k_edges_f32<<<(E + TE - 1) / TE, 256, 0, stream>>>(
            ei, eattr, xpos, h, mw1, mb1, mw2, mb2, mw3, mb3, agg, E);
        k_out<<<(N + 15) / 16, 256, 0, stream>>>(h, agg, w2, b2, w3, b3,
                                                 (float*)d_out, N);
    }
}

// Round 6
// 432.793 us; speedup vs baseline: 11.4967x; 1.0713x over previous
//
#include <hip/hip_runtime.h>
#include <math.h>

#define NCH 128
#define TE 64    // fallback edge tile
#define TF 32    // fast-path edge tile (19 KB LDS -> 8 blocks/CU)
#define AP 296   // msg_in row pad (f16): stride 148 words, uniform 8 words/bank on b128
#define WP 40    // (LDS-staged weight kernels only)
#define XP 136   // node-tile row pad (f16)

typedef __attribute__((ext_vector_type(8))) _Float16 half8;
typedef __attribute__((ext_vector_type(4))) _Float16 half4;
typedef __attribute__((ext_vector_type(4))) float f32x4;

__device__ __forceinline__ float gelu_exact(float v) {
    return 0.5f * v * (1.0f + erff(v * 0.70710678118654752f));
}

// sin/cos of (rev * 2*pi) via HW v_sin/v_cos (input in revolutions, fract-reduced)
__device__ __forceinline__ void sincos_rev(float rev, float* s, float* c) {
    float fr = rev - floorf(rev);
#if __has_builtin(__builtin_amdgcn_sinf) && __has_builtin(__builtin_amdgcn_cosf)
    *s = __builtin_amdgcn_sinf(fr);
    *c = __builtin_amdgcn_cosf(fr);
#else
    float rad = fr * 6.283185307179586f;
    *s = sinf(rad);
    *c = cosf(rad);
#endif
}

// ============ prep A: W[K][128] fp32 -> k-chunked transposed f16 [K/32][128][32]
__global__ __launch_bounds__(256) void k_prep(const float* __restrict__ W,
                                              _Float16* __restrict__ out, int total) {
    int idx = blockIdx.x * 256 + threadIdx.x;
    if (idx >= total) return;
    int k = idx >> 7, n = idx & 127;
    out[(size_t)(k >> 5) * 4096 + n * 32 + (k & 31)] = (_Float16)W[idx];
}

// ============ prep B: W[K][128] fp32 -> per-lane MFMA fragment order
// layout: [chunk][wave(4)][nf(2)][lane(64)][8 f16]
__global__ __launch_bounds__(256) void k_prep_frag(const float* __restrict__ W,
                                                   _Float16* __restrict__ out,
                                                   int nchunks) {
    int idx = blockIdx.x * 256 + threadIdx.x;
    if (idx >= nchunks * 512) return;
    int c    = idx >> 9;
    int r    = idx & 511;
    int wv   = r >> 7;
    int nf   = (r >> 6) & 1;
    int lane = r & 63;
    int n  = wv * 32 + nf * 16 + (lane & 15);
    int k0 = c * 32 + (lane >> 4) * 8;
    half8 v;
    #pragma unroll
    for (int j = 0; j < 8; ++j) v[j] = (_Float16)W[(size_t)(k0 + j) * NCH + n];
    *(half8*)(out + (size_t)idx * 8) = v;
}

// ============ Kernel 1 (fast): h = x@w1+b1 via MFMA -> h fp32 (d_out) + h2 f16
__global__ __launch_bounds__(256, 4) void k_aw1_mfma(
    const float* __restrict__ x, const _Float16* __restrict__ wc,
    const float* __restrict__ b1, float* __restrict__ h,
    _Float16* __restrict__ h2, int N)
{
    __shared__ __align__(16) _Float16 Xs[64][XP];
    __shared__ __align__(16) _Float16 Ws[128][WP];

    const int tid  = threadIdx.x;
    const int row0 = blockIdx.x * 64;
    const int lane = tid & 63;
    const int w    = tid >> 6;
    const int lrow = lane & 15;
    const int lk8  = lane >> 4;
    const int n0   = w * 32;

    const uint4* wsrc = (const uint4*)wc;
    uint4 pv0 = wsrc[tid], pv1 = wsrc[tid + 256];

    #pragma unroll
    for (int t = 0; t < 8; ++t) {
        int idx = tid + t * 256;
        int r = idx >> 5, f4 = idx & 31;
        int gr = row0 + r;
        float4 v = {0.f, 0.f, 0.f, 0.f};
        if (gr < N) v = *(const float4*)(x + (size_t)gr * NCH + f4 * 4);
        half4 p = {(_Float16)v.x, (_Float16)v.y, (_Float16)v.z, (_Float16)v.w};
        *(half4*)&Xs[r][f4 * 4] = p;
    }
    *(uint4*)&Ws[tid >> 2][(tid & 3) * 8]        = pv0;
    *(uint4*)&Ws[64 + (tid >> 2)][(tid & 3) * 8] = pv1;
    __syncthreads();

    f32x4 acc[4][2];
    #pragma unroll
    for (int mb = 0; mb < 4; ++mb)
        #pragma unroll
        for (int nf = 0; nf < 2; ++nf) acc[mb][nf] = (f32x4){0.f, 0.f, 0.f, 0.f};

    for (int i = 0; i < 4; ++i) {
        if (i < 3) {
            const uint4* s = (const uint4*)(wc + (i + 1) * 4096);
            pv0 = s[tid]; pv1 = s[tid + 256];
        }
        half8 av[4], bv[2];
        #pragma unroll
        for (int mb = 0; mb < 4; ++mb)
            av[mb] = *(const half8*)&Xs[mb * 16 + lrow][i * 32 + lk8 * 8];
        #pragma unroll
        for (int nf = 0; nf < 2; ++nf)
            bv[nf] = *(const half8*)&Ws[n0 + nf * 16 + lrow][lk8 * 8];
        #pragma unroll
        for (int mb = 0; mb < 4; ++mb)
            #pragma unroll
            for (int nf = 0; nf < 2; ++nf)
                acc[mb][nf] = __builtin_amdgcn_mfma_f32_16x16x32_f16(
                    av[mb], bv[nf], acc[mb][nf], 0, 0, 0);
        __syncthreads();
        if (i < 3) {
            *(uint4*)&Ws[tid >> 2][(tid & 3) * 8]        = pv0;
            *(uint4*)&Ws[64 + (tid >> 2)][(tid & 3) * 8] = pv1;
        }
        __syncthreads();
    }

    float bi0 = b1[n0 + lrow], bi1 = b1[n0 + 16 + lrow];
    #pragma unroll
    for (int mb = 0; mb < 4; ++mb)
        #pragma unroll
        for (int q = 0; q < 4; ++q) {
            int gr = row0 + mb * 16 + lk8 * 4 + q;
            if (gr < N) {
                float v0 = acc[mb][0][q] + bi0;
                float v1 = acc[mb][1][q] + bi1;
                h[(size_t)gr * NCH + n0 + lrow]       = v0;
                h[(size_t)gr * NCH + n0 + 16 + lrow]  = v1;
                h2[(size_t)gr * NCH + n0 + lrow]      = (_Float16)v0;
                h2[(size_t)gr * NCH + n0 + 16 + lrow] = (_Float16)v1;
            }
        }
}

// ============ Kernel 2 (fast): edge MLP — rolling B-register prefetch + setprio
__global__ __launch_bounds__(256, 8) void k_edges_mfma(
    const int* __restrict__ ei, const float* __restrict__ eattr,
    const float* __restrict__ xpos, const _Float16* __restrict__ h2,
    float* h,   // atomic target (aliases d_out)
    const _Float16* __restrict__ wf,   // fragment-packed mw1|mw2|mw3 (17 chunks)
    const float* __restrict__ mb1, const float* __restrict__ mb2,
    const float* __restrict__ mb3, int E)
{
    __shared__ __align__(16) _Float16 As[TF][AP];   // 18944 B

    const int tid  = threadIdx.x;
    const int e0   = blockIdx.x * TF;
    const int lane = tid & 63;
    const int w    = tid >> 6;
    const int lrow = lane & 15;
    const int lk8  = lane >> 4;
    const int n0   = w * 32;

    // B fragment base: wf in half8 units — chunk stride 512, wave 128, nf 64
    const half8* bp = (const half8*)wf + (w * 128 + lane);

    // ---- T14 stage: issue ALL global loads first, compute trig under them
    float4 ea[4];
    #pragma unroll
    for (int t = 0; t < 4; ++t) {
        int idx = tid + t * 256;
        int e = e0 + (idx >> 5);
        ea[t] = (e < E) ? *(const float4*)(eattr + (size_t)e * NCH + (idx & 31) * 4)
                        : (float4){0.f, 0.f, 0.f, 0.f};
    }
    uint4 hv[2];
    #pragma unroll
    for (int t = 0; t < 2; ++t) {
        int idx = tid + t * 256;
        int e = e0 + (idx >> 4);
        int s = (e < E) ? ei[e] : 0;
        hv[t] = *(const uint4*)(h2 + (size_t)s * NCH + (idx & 15) * 8);
    }
    // prefetch first two B chunks while staging/trig runs
    half8 b[2][2];
    b[0][0] = bp[0];         b[0][1] = bp[64];
    b[1][0] = bp[512];       b[1][1] = bp[512 + 64];

    // trig: 8 threads per edge, 2 (sin,cos) pairs each — HW v_sin/v_cos
    {
        int le = tid >> 3, i0 = tid & 7;
        int ge = e0 + le;
        float r = 0.f;
        if (ge < E) {
            int s = ei[ge], d = ei[E + ge];
            float dx = xpos[d * 3 + 0] - xpos[s * 3 + 0];
            float dy = xpos[d * 3 + 1] - xpos[s * 3 + 1];
            float dz = xpos[d * 3 + 2] - xpos[s * 3 + 2];
            r = sqrtf(dx * dx + dy * dy + dz * dz);
        }
        #pragma unroll
        for (int u = 0; u < 2; ++u) {
            int i = i0 + u * 8;
            // omega_i/(2*pi) = 10*128^(1-i/8) * 0.15915494
            float omr = 1.5915494309f * exp2f(7.0f - 0.875f * (float)i);
            float sv, cv;
            sincos_rev(r * omr, &sv, &cv);
            As[le][i]      = (_Float16)sv;
            As[le][16 + i] = (_Float16)cv;
        }
    }
    // write-late: convert eattr, copy h2
    #pragma unroll
    for (int t = 0; t < 4; ++t) {
        int idx = tid + t * 256;
        half4 p = {(_Float16)ea[t].x, (_Float16)ea[t].y,
                   (_Float16)ea[t].z, (_Float16)ea[t].w};
        *(half4*)&As[idx >> 5][32 + (idx & 31) * 4] = p;
    }
    #pragma unroll
    for (int t = 0; t < 2; ++t) {
        int idx = tid + t * 256;
        *(uint4*)&As[idx >> 4][160 + (idx & 15) * 8] = hv[t];
    }
    __syncthreads();

    f32x4 acc[2][2];
    #pragma unroll
    for (int mb = 0; mb < 2; ++mb)
        #pragma unroll
        for (int nf = 0; nf < 2; ++nf) acc[mb][nf] = (f32x4){0.f, 0.f, 0.f, 0.f};

    auto epi = [&](const float* __restrict__ mbv) {
        float bi0 = mbv[n0 + lrow], bi1 = mbv[n0 + 16 + lrow];
        #pragma unroll
        for (int mb = 0; mb < 2; ++mb)
            #pragma unroll
            for (int nf = 0; nf < 2; ++nf) {
                float bb = nf ? bi1 : bi0;
                #pragma unroll
                for (int q = 0; q < 4; ++q) {
                    float g = gelu_exact(acc[mb][nf][q] + bb);
                    As[mb * 16 + lk8 * 4 + q][n0 + nf * 16 + lrow] = (_Float16)g;
                }
                acc[mb][nf] = (f32x4){0.f, 0.f, 0.f, 0.f};
            }
    };

    // ---- flat 17-chunk pipeline (9 layer1 | 4 layer2 | 4 layer3),
    //      2-slot rolling register prefetch of B, barriers only at layer edges
    #pragma unroll
    for (int i = 0; i < 17; ++i) {
        const int s  = i & 1;                                 // static under unroll
        const int lc = (i < 9) ? i : (i < 13) ? (i - 9) : (i - 13);
        half8 av0 = *(const half8*)&As[lrow][lc * 32 + lk8 * 8];
        half8 av1 = *(const half8*)&As[16 + lrow][lc * 32 + lk8 * 8];
        __builtin_amdgcn_s_setprio(1);
        acc[0][0] = __builtin_amdgcn_mfma_f32_16x16x32_f16(av0, b[s][0], acc[0][0], 0, 0, 0);
        acc[0][1] = __builtin_amdgcn_mfma_f32_16x16x32_f16(av0, b[s][1], acc[0][1], 0, 0, 0);
        acc[1][0] = __builtin_amdgcn_mfma_f32_16x16x32_f16(av1, b[s][0], acc[1][0], 0, 0, 0);
        acc[1][1] = __builtin_amdgcn_mfma_f32_16x16x32_f16(av1, b[s][1], acc[1][1], 0, 0, 0);
        __builtin_amdgcn_s_setprio(0);
        if (i + 2 < 17) {   // refill the slot just consumed (ready at chunk i+2)
            b[s][0] = bp[(size_t)(i + 2) * 512];
            b[s][1] = bp[(size_t)(i + 2) * 512 + 64];
        }
        if (i == 8)  { __syncthreads(); epi(mb1); __syncthreads(); }
        if (i == 12) { __syncthreads(); epi(mb2); __syncthreads(); }
    }

    // ---- bias + scatter-add into h
    {
        float bi0 = mb3[n0 + lrow], bi1 = mb3[n0 + 16 + lrow];
        #pragma unroll
        for (int mb = 0; mb < 2; ++mb)
            #pragma unroll
            for (int q = 0; q < 4; ++q) {
                int e = e0 + mb * 16 + lk8 * 4 + q;
                if (e < E) {
                    int d = ei[E + e];
                    atomicAdd(h + (size_t)d * NCH + n0 + lrow,      acc[mb][0][q] + bi0);
                    atomicAdd(h + (size_t)d * NCH + n0 + 16 + lrow, acc[mb][1][q] + bi1);
                }
            }
    }
}

// ============ Kernel 3 (fast): out = relu(h@w2+b2)@w3+b3 via MFMA, in-place
__global__ __launch_bounds__(256, 4) void k_out_mfma(
    const float* h, const _Float16* __restrict__ w2c,
    const float* __restrict__ b2, const _Float16* __restrict__ w3c,
    const float* __restrict__ b3, float* out, int N)
{
    __shared__ __align__(16) _Float16 Xs[64][XP];
    __shared__ __align__(16) _Float16 Ws[128][WP];

    const int tid  = threadIdx.x;
    const int row0 = blockIdx.x * 64;
    const int lane = tid & 63;
    const int w    = tid >> 6;
    const int lrow = lane & 15;
    const int lk8  = lane >> 4;
    const int n0   = w * 32;

    const uint4* wsrc = (const uint4*)w2c;
    uint4 pv0 = wsrc[tid], pv1 = wsrc[tid + 256];

    #pragma unroll
    for (int t = 0; t < 8; ++t) {
        int idx = tid + t * 256;
        int r = idx >> 5, f4 = idx & 31;
        int gr = row0 + r;
        float4 v = {0.f, 0.f, 0.f, 0.f};
        if (gr < N) v = *(const float4*)(h + (size_t)gr * NCH + f4 * 4);
        half4 p = {(_Float16)v.x, (_Float16)v.y, (_Float16)v.z, (_Float16)v.w};
        *(half4*)&Xs[r][f4 * 4] = p;
    }
    *(uint4*)&Ws[tid >> 2][(tid & 3) * 8]        = pv0;
    *(uint4*)&Ws[64 + (tid >> 2)][(tid & 3) * 8] = pv1;
    __syncthreads();

    f32x4 acc[4][2];
    #pragma unroll
    for (int mb = 0; mb < 4; ++mb)
        #pragma unroll
        for (int nf = 0; nf < 2; ++nf) acc[mb][nf] = (f32x4){0.f, 0.f, 0.f, 0.f};

    for (int i = 0; i < 8; ++i) {
        if (i < 7) {
            int j = i + 1;
            const _Float16* nw = (j < 4) ? (w2c + j * 4096) : (w3c + (j - 4) * 4096);
            const uint4* s = (const uint4*)nw;
            pv0 = s[tid]; pv1 = s[tid + 256];
        }
        const int lc = i & 3;
        half8 av[4], bv[2];
        #pragma unroll
        for (int mb = 0; mb < 4; ++mb)
            av[mb] = *(const half8*)&Xs[mb * 16 + lrow][lc * 32 + lk8 * 8];
        #pragma unroll
        for (int nf = 0; nf < 2; ++nf)
            bv[nf] = *(const half8*)&Ws[n0 + nf * 16 + lrow][lk8 * 8];
        #pragma unroll
        for (int mb = 0; mb < 4; ++mb)
            #pragma unroll
            for (int nf = 0; nf < 2; ++nf)
                acc[mb][nf] = __builtin_amdgcn_mfma_f32_16x16x32_f16(
                    av[mb], bv[nf], acc[mb][nf], 0, 0, 0);

        __syncthreads();
        if (i == 3) {
            float bi0 = b2[n0 + lrow], bi1 = b2[n0 + 16 + lrow];
            #pragma unroll
            for (int mb = 0; mb < 4; ++mb)
                #pragma unroll
                for (int nf = 0; nf < 2; ++nf) {
                    float bb = nf ? bi1 : bi0;
                    #pragma unroll
                    for (int q = 0; q < 4; ++q) {
                        float g = fmaxf(acc[mb][nf][q] + bb, 0.f);
                        Xs[mb * 16 + lk8 * 4 + q][n0 + nf * 16 + lrow] = (_Float16)g;
                    }
                    acc[mb][nf] = (f32x4){0.f, 0.f, 0.f, 0.f};
                }
        }
        if (i < 7) {
            *(uint4*)&Ws[tid >> 2][(tid & 3) * 8]        = pv0;
            *(uint4*)&Ws[64 + (tid >> 2)][(tid & 3) * 8] = pv1;
        }
        __syncthreads();
    }

    float bi0 = b3[n0 + lrow], bi1 = b3[n0 + 16 + lrow];
    #pragma unroll
    for (int mb = 0; mb < 4; ++mb)
        #pragma unroll
        for (int q = 0; q < 4; ++q) {
            int gr = row0 + mb * 16 + lk8 * 4 + q;
            if (gr < N) {
                out[(size_t)gr * NCH + n0 + lrow]      = acc[mb][0][q] + bi0;
                out[(size_t)gr * NCH + n0 + 16 + lrow] = acc[mb][1][q] + bi1;
            }
        }
}

// ==================== fp32 fallback path (round-1, proven) ====================
__global__ __launch_bounds__(256) void k_atomwise1(
    const float* __restrict__ x, const float* __restrict__ w1,
    const float* __restrict__ b1, float* __restrict__ h,
    float* __restrict__ h2, int N)
{
    __shared__ float xs[16][NCH];
    const int row0 = blockIdx.x * 16;
    const int tid = threadIdx.x;
    #pragma unroll
    for (int t = 0; t < 8; ++t) {
        int idx = tid + t * 256;
        int r = idx >> 7, c = idx & 127;
        int gr = row0 + r;
        xs[r][c] = (gr < N) ? x[(size_t)gr * NCH + c] : 0.f;
    }
    __syncthreads();
    const int j = tid & 127;
    const int rg = tid >> 7;
    float acc[8];
    #pragma unroll
    for (int i = 0; i < 8; ++i) acc[i] = 0.f;
    for (int k = 0; k < NCH; ++k) {
        float wv = w1[(size_t)k * NCH + j];
        #pragma unroll
        for (int i = 0; i < 8; ++i)
            acc[i] = fmaf(xs[rg * 8 + i][k], wv, acc[i]);
    }
    float bv = b1[j];
    #pragma unroll
    for (int i = 0; i < 8; ++i) {
        int gr = row0 + rg * 8 + i;
        if (gr < N) {
            float v = acc[i] + bv;
            h[(size_t)gr * NCH + j]  = v;
            h2[(size_t)gr * NCH + j] = v;
        }
    }
}

__global__ __launch_bounds__(256) void k_edges_f32(
    const int* __restrict__ ei, const float* __restrict__ eattr,
    const float* __restrict__ xpos, const float* __restrict__ h,
    const float* __restrict__ mw1, const float* __restrict__ mb1,
    const float* __restrict__ mw2, const float* __restrict__ mb2,
    const float* __restrict__ mw3, const float* __restrict__ mb3,
    float* __restrict__ agg, int E)
{
    __shared__ __align__(16) float Asf[TE][292];
    __shared__ float Wsf[32][NCH];
    __shared__ int srcS[TE];
    __shared__ int dstS[TE];
    const int tid = threadIdx.x;
    const int e0 = blockIdx.x * TE;
    if (tid < TE) {
        int e = e0 + tid;
        int s = 0, d = -1;
        float r = 0.f;
        if (e < E) {
            s = ei[e]; d = ei[E + e];
            float dx = xpos[d * 3 + 0] - xpos[s * 3 + 0];
            float dy = xpos[d * 3 + 1] - xpos[s * 3 + 1];
            float dz = xpos[d * 3 + 2] - xpos[s * 3 + 2];
            r = sqrtf(dx * dx + dy * dy + dz * dz);
        }
        srcS[tid] = s; dstS[tid] = d;
        #pragma unroll
        for (int i = 0; i < 16; ++i) {
            float om = 10.f * exp2f(7.0f - 0.875f * (float)i);
            float f = r * om;
            Asf[tid][i] = sinf(f); Asf[tid][16 + i] = cosf(f);
        }
    }
    __syncthreads();
    {
        const int half = tid >> 7;
        const int c = tid & 127;
        for (int ee = 0; ee < TE; ee += 2) {
            int le = ee + half;
            int e = e0 + le;
            if (e < E) {
                Asf[le][32 + c]  = eattr[(size_t)e * NCH + c];
                Asf[le][160 + c] = h[(size_t)srcS[le] * NCH + c];
            } else { Asf[le][32 + c] = 0.f; Asf[le][160 + c] = 0.f; }
        }
    }
    const int jl = tid & 31;
    const int g  = tid >> 5;
    float acc[8][4];
    auto run_layer = [&](const float* __restrict__ Wg, int K) {
        #pragma unroll
        for (int i = 0; i < 8; ++i)
            #pragma unroll
            for (int c = 0; c < 4; ++c) acc[i][c] = 0.f;
        for (int k0 = 0; k0 < K; k0 += 32) {
            __syncthreads();
            #pragma unroll
            for (int t = 0; t < 16; ++t) {
                int idx = tid + t * 256;
                Wsf[idx >> 7][idx & 127] =
                    Wg[(size_t)(k0 + (idx >> 7)) * NCH + (idx & 127)];
            }
            __syncthreads();
            #pragma unroll
            for (int kk = 0; kk < 32; kk += 4) {
                float4 a[8];
                #pragma unroll
                for (int i = 0; i < 8; ++i)
                    a[i] = *reinterpret_cast<const float4*>(&Asf[g * 8 + i][k0 + kk]);
                #pragma unroll
                for (int u = 0; u < 4; ++u) {
                    float w0 = Wsf[kk + u][jl];
                    float w1v = Wsf[kk + u][jl + 32];
                    float w2v = Wsf[kk + u][jl + 64];
                    float w3v = Wsf[kk + u][jl + 96];
                    #pragma unroll
                    for (int i = 0; i < 8; ++i) {
                        float avv = (&a[i].x)[u];
                        acc[i][0] = fmaf(avv, w0, acc[i][0]);
                        acc[i][1] = fmaf(avv, w1v, acc[i][1]);
                        acc[i][2] = fmaf(avv, w2v, acc[i][2]);
                        acc[i][3] = fmaf(avv, w3v, acc[i][3]);
                    }
                }
            }
        }
    };
    run_layer(mw1, 288);
    #pragma unroll
    for (int i = 0; i < 8; ++i)
        #pragma unroll
        for (int c = 0; c < 4; ++c) {
            int j = jl + 32 * c;
            Asf[g * 8 + i][j] = gelu_exact(acc[i][c] + mb1[j]);
        }
    run_layer(mw2, 128);
    #pragma unroll
    for (int i = 0; i < 8; ++i)
        #pragma unroll
        for (int c = 0; c < 4; ++c) {
            int j = jl + 32 * c;
            Asf[g * 8 + i][j] = gelu_exact(acc[i][c] + mb2[j]);
        }
    run_layer(mw3, 128);
    #pragma unroll
    for (int i = 0; i < 8; ++i) {
        int d = dstS[g * 8 + i];
        if (d >= 0) {
            #pragma unroll
            for (int c = 0; c < 4; ++c) {
                int j = jl + 32 * c;
                atomicAdd(&agg[(size_t)d * NCH + j], acc[i][c] + mb3[j]);
            }
        }
    }
}

__global__ __launch_bounds__(256) void k_out(
    const float* h, const float* aggOpt,
    const float* __restrict__ w2, const float* __restrict__ b2,
    const float* __restrict__ w3, const float* __restrict__ b3,
    float* out, int N)
{
    __shared__ float hs[16][NCH];
    __shared__ float ts[16][NCH];
    const int row0 = blockIdx.x * 16;
    const int tid = threadIdx.x;
    #pragma unroll
    for (int t = 0; t < 8; ++t) {
        int idx = tid + t * 256;
        int r = idx >> 7, c = idx & 127;
        int gr = row0 + r;
        float v = 0.f;
        if (gr < N) {
            v = h[(size_t)gr * NCH + c];
            if (aggOpt) v += aggOpt[(size_t)gr * NCH + c];
        }
        hs[r][c] = v;
    }
    __syncthreads();
    const int j = tid & 127;
    const int rg = tid >> 7;
    float acc[8];
    #pragma unroll
    for (int i = 0; i < 8; ++i) acc[i] = 0.f;
    for (int k = 0; k < NCH; ++k) {
        float wv = w2[(size_t)k * NCH + j];
        #pragma unroll
        for (int i = 0; i < 8; ++i)
            acc[i] = fmaf(hs[rg * 8 + i][k], wv, acc[i]);
    }
    float bv = b2[j];
    #pragma unroll
    for (int i = 0; i < 8; ++i)
        ts[rg * 8 + i][j] = fmaxf(acc[i] + bv, 0.f);
    __syncthreads();
    float acc2[8];
    #pragma unroll
    for (int i = 0; i < 8; ++i) acc2[i] = 0.f;
    for (int k = 0; k < NCH; ++k) {
        float wv = w3[(size_t)k * NCH + j];
        #pragma unroll
        for (int i = 0; i < 8; ++i)
            acc2[i] = fmaf(ts[rg * 8 + i][k], wv, acc2[i]);
    }
    float b3v = b3[j];
    #pragma unroll
    for (int i = 0; i < 8; ++i) {
        int gr = row0 + rg * 8 + i;
        if (gr < N) out[(size_t)gr * NCH + j] = acc2[i] + b3v;
    }
}

extern "C" void kernel_launch(void* const* d_in, const int* in_sizes, int n_in,
                              void* d_out, int out_size, void* d_ws, size_t ws_size,
                              hipStream_t stream)
{
    const float* x     = (const float*)d_in[0];
    const int*   ei    = (const int*)d_in[1];
    const float* eattr = (const float*)d_in[2];
    const float* xpos  = (const float*)d_in[3];
    const float* w1    = (const float*)d_in[4];
    const float* b1    = (const float*)d_in[5];
    const float* mw1   = (const float*)d_in[6];
    const float* mb1   = (const float*)d_in[7];
    const float* mw2   = (const float*)d_in[8];
    const float* mb2   = (const float*)d_in[9];
    const float* mw3   = (const float*)d_in[10];
    const float* mb3   = (const float*)d_in[11];
    const float* w2    = (const float*)d_in[12];
    const float* b2    = (const float*)d_in[13];
    const float* w3    = (const float*)d_in[14];
    const float* b3    = (const float*)d_in[15];

    const int N = in_sizes[0] / NCH;
    const int E = in_sizes[1] / 2;

    float* h = (float*)d_out;

    const size_t h2_bytes = (size_t)N * NCH * sizeof(_Float16);
    const size_t wchunks  = 17 + 4 + 4 + 4;   // wf(mw1|mw2|mw3) + aw1 + o2 + o3
    const size_t wbytes   = wchunks * 4096 * sizeof(_Float16);
    const bool fast = ws_size >= h2_bytes + wbytes;

    if (fast) {
        _Float16* h2   = (_Float16*)d_ws;
        _Float16* wf   = (_Float16*)((char*)d_ws + h2_bytes);  // 17 chunks, frag order
        _Float16* aw1c = wf + 17 * 4096;
        _Float16* o2c  = aw1c + 4 * 4096;
        _Float16* o3c  = o2c + 4 * 4096;
        k_prep_frag<<<18, 256, 0, stream>>>(mw1, wf, 9);
        k_prep_frag<<<8, 256, 0, stream>>>(mw2, wf + 9 * 4096, 4);
        k_prep_frag<<<8, 256, 0, stream>>>(mw3, wf + 13 * 4096, 4);
        k_prep<<<64, 256, 0, stream>>>(w1, aw1c, 128 * 128);
        k_prep<<<64, 256, 0, stream>>>(w2, o2c, 128 * 128);
        k_prep<<<64, 256, 0, stream>>>(w3, o3c, 128 * 128);
        const int nb = (N + 63) / 64;
        k_aw1_mfma<<<nb, 256, 0, stream>>>(x, aw1c, b1, h, h2, N);
        k_edges_mfma<<<(E + TF - 1) / TF, 256, 0, stream>>>(
            ei, eattr, xpos, h2, h, wf, mb1, mb2, mb3, E);
        k_out_mfma<<<nb, 256, 0, stream>>>(h, o2c, b2, o3c, b3, (float*)d_out, N);
    } else {
        float* agg = (float*)d_ws;
        k_atomwise1<<<(N + 15) / 16, 256, 0, stream>>>(x, w1, b1, h, agg, N);
        hipMemsetAsync(agg, 0, (size_t)N * NCH * sizeof(float), stream);
        k_edges_f32<<<(E + TE - 1) / TE, 256, 0, stream>>>(
            ei, eattr, xpos, h, mw1, mb1, mw2, mb2, mw3, mb3, agg, E);
        k_out<<<(N + 15) / 16, 256, 0, stream>>>(h, agg, w2, b2, w3, b3,
                                                 (float*)d_out, N);
    }
}